// Round 15
// baseline (17332.835 us; speedup 1.0000x reference)
//
#include <hip/hip_runtime.h>

typedef unsigned short u16;
typedef unsigned int   u32;

using f32x4  = __attribute__((ext_vector_type(4))) float;
using bf16x8 = __attribute__((ext_vector_type(8))) short;  // 8 bf16 in 4 VGPRs

__device__ __forceinline__ float bf2f(u16 u){
  union { u32 i; float f; } x; x.i = ((u32)u) << 16; return x.f;
}
__device__ __forceinline__ u16 f2bf(float f){
  union { float f; u32 i; } x; x.f = f;
  u32 r = x.i + 0x7FFFu + ((x.i >> 16) & 1u);   // RNE
  return (u16)(r >> 16);
}
// tanh-form GELU, safe at +/-inf exp: tanh(u) = 1 - 2/(e^{2u}+1)
__device__ __forceinline__ float gelu_f(float v){
  float u = 0.7978845608f * v * (1.f + 0.044715f*v*v);
  float e = __expf(2.f*u);
  return 0.5f*v*(2.f - 2.f/(e + 1.f));
}

// async global->LDS, 16B per lane. LDS dest = wave-uniform base + lane*16 (HW);
// global source address is per-lane (enables row-gather + pre-swizzled staging).
__device__ __forceinline__ void glds16(const void* g, void* l){
  __builtin_amdgcn_global_load_lds(
      (const __attribute__((address_space(1))) unsigned int*)g,
      (__attribute__((address_space(3))) unsigned int*)(unsigned int)(unsigned long long)l,
      16, 0, 0);
}

// window-order token m -> source row in x (roll by -3,-3 then 7x7 window partition)
__device__ __forceinline__ int rollmap(int m){
  int win = m / 49, n = m % 49;
  int b  = win >> 6, wi = win & 63;
  int wh = wi >> 3, ww = wi & 7;
  int r = n / 7, c = n % 7;
  int sh = wh*7 + r + 3; if (sh >= 56) sh -= 56;
  int sw = ww*7 + c + 3; if (sw >= 56) sw -= 56;
  return b*3136 + sh*56 + sw;
}

// row-swizzled 16B-chunk offset within a [256 rows][32k] 64B-row region (R9-verified)
__device__ __forceinline__ int rowswz(int r, int ck){
  return ((r>>1)<<7) + (((((r&1)<<2)|ck) ^ ((r>>1)&7))<<4);
}

// ---------------- GEMM: C[M,N] = A[M,K] @ W[N,K]^T + bias ----------------
// BM=BN=256, BK=32; 512 thr / 8 waves (2Mx4N), per-wave 128x64 output.
// A: LDS 3 x 16KB ring (depth-2 stage via glds16, R9 pre-swizzle).
// B: DIRECT from global into registers (fb[4] = 4 x dwordx4, 16 cache lines
//    per instr, L2-hot), double-buffered fbA/fbB one tile ahead.
// This halves LDS traffic and drops LDS to 48KB -> 3 blocks/CU (TLP overlaps
// one block's LDS/barrier window with another's MFMA burst).
// Per tile: issue [4 fb loads, 2 stgA] -> 2 MFMA phases (lgkm-gated) ->
// vmcnt(2) (drains stgA(T+1)+fb(T+1), leaves stgA(T+2)) -> 1 barrier.
// AMODE 0: A row-major. AMODE 2: roll/window row-gather.
// EPI 0: bf16 out. EPI 2: bf16 out + GELU.
template<int EPI, int AMODE, int NKT>
__global__ __launch_bounds__(512, 6) void gemm_bt(const u16* __restrict__ A,
      const u16* __restrict__ Bw, const float* __restrict__ bias,
      void* __restrict__ outp, int M, int N, int nbn)
{
  constexpr int K = NKT * 32;
  __shared__ __align__(16) char LDS[3*16384];   // 48 KB: A ring only
  const int t    = threadIdx.x;
  const int lane = t & 63, wave = t >> 6;
  const int wr = wave >> 2, wn = wave & 3;
  const int lr = lane & 15, lk = lane >> 4;

  // XCD-chunked block swizzle; bn fastest (A-panel shared by consecutive blocks).
  const int gl = ((blockIdx.x & 7) * ((int)gridDim.x >> 3)) + (blockIdx.x >> 3);
  const int bm = gl / nbn, bn = gl - bm*nbn;

  // ---- A staging source (pre-swizzled R9 formula) ----
  const int q   = (t & 7) ^ ((t >> 3) & 7);
  const int sr0 = 2*(t >> 3) + (q >> 2);
  const int sch = (q & 3) * 8;
  const u16 *pA0, *pA1;
  if constexpr (AMODE == 0){
    pA0 = A + (size_t)(bm*256 + sr0      )*K + sch;
    pA1 = A + (size_t)(bm*256 + sr0 + 128)*K + sch;
  } else {
    pA0 = A + (size_t)rollmap(bm*256 + sr0      )*K + sch;
    pA1 = A + (size_t)rollmap(bm*256 + sr0 + 128)*K + sch;
  }
  // ---- B-direct per-lane fragment bases ----
  const u16* pB[4];
#pragma unroll
  for (int j = 0; j < 4; ++j)
    pB[j] = Bw + (size_t)(bn*256 + wn*64 + j*16 + lr)*K + lk*8;

  int oA[8];
#pragma unroll
  for (int i = 0; i < 8; ++i) oA[i] = rowswz(wr*128 + i*16 + lr, lk);

  f32x4 acc[8][4];
#pragma unroll
  for (int i = 0; i < 8; ++i)
#pragma unroll
    for (int j = 0; j < 4; ++j) acc[i][j] = (f32x4){0.f, 0.f, 0.f, 0.f};

  auto stgA = [&](int T, int buf){
    char* d = LDS + buf*16384 + wave*1024;
    const int e = T*32;
    glds16(pA0 + e, d);
    glds16(pA1 + e, d + 8192);
  };
  auto ldB = [&](int T, bf16x8 (&fb)[4]){
#pragma unroll
    for (int j = 0; j < 4; ++j)
      fb[j] = *(const bf16x8*)(pB[j] + T*32);
  };

  bf16x8 fbA[4], fbB[4];

  // ---- prologue: fb(0) + A tiles 0,1 ----
  ldB(0, fbA);          // 4 loads (oldest)
  stgA(0, 0);           // 2
  stgA(1, 1);           // 2 (youngest)
  asm volatile("s_waitcnt vmcnt(2)" ::: "memory");   // fb0 + stgA0 done; stgA1 flies
  __builtin_amdgcn_s_barrier();
  asm volatile("" ::: "memory");

  auto TILE = [&](int T, int bcur, bf16x8 (&fbu)[4], bf16x8 (&fbl)[4]){
    if (T + 1 < NKT) ldB(T + 1, fbl);               // 4 vm loads (older)
    if (T + 2 < NKT){
      int bs = bcur + 2; if (bs >= 3) bs -= 3;
      stgA(T + 2, bs);                              // 2 vm loads (younger)
    }
    const char* ld = LDS + bcur*16384;
    bf16x8 fa[4];
#pragma unroll
    for (int i = 0; i < 4; ++i) fa[i] = *(const bf16x8*)(ld + oA[i]);
    asm volatile("s_waitcnt lgkmcnt(0)" ::: "memory");
    __builtin_amdgcn_sched_barrier(0);
    __builtin_amdgcn_s_setprio(1);
#pragma unroll
    for (int i = 0; i < 4; ++i)
#pragma unroll
      for (int j = 0; j < 4; ++j)
        acc[i][j] = __builtin_amdgcn_mfma_f32_16x16x32_bf16(fa[i], fbu[j], acc[i][j], 0, 0, 0);
    __builtin_amdgcn_s_setprio(0);
#pragma unroll
    for (int i = 0; i < 4; ++i) fa[i] = *(const bf16x8*)(ld + oA[4+i]);
    asm volatile("s_waitcnt lgkmcnt(0)" ::: "memory");
    __builtin_amdgcn_sched_barrier(0);
    __builtin_amdgcn_s_setprio(1);
#pragma unroll
    for (int i = 0; i < 4; ++i)
#pragma unroll
      for (int j = 0; j < 4; ++j)
        acc[4+i][j] = __builtin_amdgcn_mfma_f32_16x16x32_bf16(fa[i], fbu[j], acc[4+i][j], 0, 0, 0);
    __builtin_amdgcn_s_setprio(0);
    // drain: stgA(T+1) (issued last tile) + fb(T+1); stgA(T+2) stays in flight
    if (T + 2 < NKT)      asm volatile("s_waitcnt vmcnt(2)" ::: "memory");
    else if (T + 1 < NKT) asm volatile("s_waitcnt vmcnt(0)" ::: "memory");
    if (T + 1 < NKT){
      __builtin_amdgcn_s_barrier();
      asm volatile("" ::: "memory");
    }
  };

  int bcur = 0;
  for (int p = 0; p < NKT/2; ++p){
    TILE(2*p,     bcur, fbA, fbB);  bcur = (bcur == 2) ? 0 : bcur + 1;
    TILE(2*p + 1, bcur, fbB, fbA);  bcur = (bcur == 2) ? 0 : bcur + 1;
  }

  // ---- epilogue ----
  const int lc = lane & 15, lg = lane >> 4;
#pragma unroll
  for (int i = 0; i < 8; ++i){
#pragma unroll
    for (int j = 0; j < 4; ++j){
      int cm = bm*256 + wr*128 + i*16 + lg*4;
      int cn = bn*256 + wn*64  + j*16 + lc;
      float bv = bias[cn];
#pragma unroll
      for (int r = 0; r < 4; ++r){
        float v = acc[i][j][r] + bv;
        if (EPI == 2) v = gelu_f(v);
        ((u16*)outp)[(size_t)(cm + r)*N + cn] = f2bf(v);
      }
    }
  }
}

// ---------------- MFMA attention: 1 wave per (window, head), 4 waves/block ----
__global__ __launch_bounds__(256, 2) void attn_mfma(const u16* __restrict__ qkv,
      const float* __restrict__ rpb, const float* __restrict__ ls,
      u16* __restrict__ outp)
{
  __shared__ __align__(16) u16 Pl[4][64*72];
  __shared__ __align__(16) u16 Vl[4][32*72];
  __shared__ unsigned char regid[64];
  const int tid  = threadIdx.x, lane = tid & 63, wave = tid >> 6;
  const int lc = lane & 15, lg = lane >> 4;
  const int pair = blockIdx.x*4 + wave;
  const int win = pair >> 4, h = pair & 15;

  const u16* qb = qkv + (size_t)win*49*1536 + h*32;
  const u16* kb = qb + 512;
  const u16* vb = qb + 1024;

  if (tid < 49){
    int wi = win & 63, wh = wi >> 3, ww = wi & 7;
    int q7 = (tid*37) >> 8, r7 = tid - q7*7;
    int gh = wh*7 + q7, gw = ww*7 + r7;
    int rh = gh < 49 ? 0 : (gh < 53 ? 1 : 2);
    int rw = gw < 49 ? 0 : (gw < 53 ? 1 : 2);
    regid[tid] = (unsigned char)(rh*3 + rw);
  }

  u16* V = &Vl[wave][0];
#pragma unroll
  for (int it = 0; it < 4; ++it){
    int ch = it*64 + lane;
    int n = ch >> 2, oct = ch & 3;
    union { int4 i4; u16 s[8]; } v8;
    if (n < 49) v8.i4 = *(const int4*)(vb + (size_t)n*1536 + oct*8);
    else        v8.i4 = make_int4(0,0,0,0);
#pragma unroll
    for (int q = 0; q < 8; ++q) V[(oct*8 + q)*72 + n] = v8.s[q];
  }

  const float scale = __expf(fminf(ls[h], 4.6051702f));
  bf16x8 qf[4], kf[4];
#pragma unroll
  for (int ti = 0; ti < 4; ++ti){
    const int n = ti*16 + lc;
    {
      union { int4 i4; u16 s[8]; } raw;
      raw.i4 = *(const int4*)(qb + (size_t)n*1536 + lg*8);
      float f[8]; float ss = 0.f;
#pragma unroll
      for (int q = 0; q < 8; ++q){ f[q] = bf2f(raw.s[q]); ss += f[q]*f[q]; }
      ss += __shfl_xor(ss, 16); ss += __shfl_xor(ss, 32);
      const float inv = scale / fmaxf(sqrtf(ss), 1e-12f);
      union { short s[8]; bf16x8 v; } o;
#pragma unroll
      for (int q = 0; q < 8; ++q) o.s[q] = (short)f2bf(f[q]*inv);
      qf[ti] = o.v;
    }
    {
      union { int4 i4; u16 s[8]; } raw;
      raw.i4 = *(const int4*)(kb + (size_t)n*1536 + lg*8);
      float f[8]; float ss = 0.f;
#pragma unroll
      for (int q = 0; q < 8; ++q){ f[q] = bf2f(raw.s[q]); ss += f[q]*f[q]; }
      ss += __shfl_xor(ss, 16); ss += __shfl_xor(ss, 32);
      const float inv = 1.f / fmaxf(sqrtf(ss), 1e-12f);
      union { short s[8]; bf16x8 v; } o;
#pragma unroll
      for (int q = 0; q < 8; ++q) o.s[q] = (short)f2bf(f[q]*inv);
      kf[ti] = o.v;
    }
  }
  __syncthreads();

  f32x4 acc[4][4];
#pragma unroll
  for (int i = 0; i < 4; ++i)
#pragma unroll
    for (int j = 0; j < 4; ++j) acc[i][j] = (f32x4){0.f,0.f,0.f,0.f};
#pragma unroll
  for (int i = 0; i < 4; ++i)
#pragma unroll
    for (int j = 0; j < 4; ++j)
      acc[i][j] = __builtin_amdgcn_mfma_f32_16x16x32_bf16(qf[i], kf[j], acc[i][j], 0, 0, 0);

  u16* P = &Pl[wave][0];
  int rj[4];
#pragma unroll
  for (int tj = 0; tj < 4; ++tj){
    int j = tj*16 + lc;
    rj[tj] = (int)regid[j < 49 ? j : 0];
  }
  const float* rpbh = rpb + h*2401;
#pragma unroll
  for (int ti = 0; ti < 4; ++ti){
#pragma unroll
    for (int r = 0; r < 4; ++r){
      const int i = ti*16 + lg*4 + r;
      const bool iv = i < 49;
      const int ic = iv ? i : 0;
      const int ri = (int)regid[ic];
      const float* rrow = rpbh + ic*49;
      float sv[4];
#pragma unroll
      for (int tj = 0; tj < 4; ++tj){
        const int j = tj*16 + lc;
        float t2 = acc[ti][tj][r] + rrow[j < 49 ? j : 0];
        if (ri != rj[tj]) t2 -= 100.f;
        sv[tj] = (iv && j < 49) ? t2 : -1e30f;
      }
      float mx = fmaxf(fmaxf(sv[0],sv[1]), fmaxf(sv[2],sv[3]));
      mx = fmaxf(mx, __shfl_xor(mx, 1));
      mx = fmaxf(mx, __shfl_xor(mx, 2));
      mx = fmaxf(mx, __shfl_xor(mx, 4));
      mx = fmaxf(mx, __shfl_xor(mx, 8));
      float p[4], sum = 0.f;
#pragma unroll
      for (int tj = 0; tj < 4; ++tj){ p[tj] = __expf(sv[tj] - mx); sum += p[tj]; }
      sum += __shfl_xor(sum, 1); sum += __shfl_xor(sum, 2);
      sum += __shfl_xor(sum, 4); sum += __shfl_xor(sum, 8);
      const float rs = __builtin_amdgcn_rcpf(sum);
#pragma unroll
      for (int tj = 0; tj < 4; ++tj) P[i*72 + tj*16 + lc] = f2bf(p[tj]*rs);
    }
  }
  __syncthreads();

  f32x4 o[4][2];
#pragma unroll
  for (int i = 0; i < 4; ++i){ o[i][0] = (f32x4){0.f,0.f,0.f,0.f}; o[i][1] = (f32x4){0.f,0.f,0.f,0.f}; }
#pragma unroll
  for (int ks = 0; ks < 2; ++ks){
    bf16x8 pa[4], vf[2];
#pragma unroll
    for (int ti = 0; ti < 4; ++ti)
      pa[ti] = *(const bf16x8*)((const char*)P + (ti*16 + lc)*144 + (ks*4 + lg)*16);
#pragma unroll
    for (int tc = 0; tc < 2; ++tc)
      vf[tc] = *(const bf16x8*)((const char*)V + (tc*16 + lc)*144 + (ks*4 + lg)*16);
#pragma unroll
    for (int ti = 0; ti < 4; ++ti)
#pragma unroll
      for (int tc = 0; tc < 2; ++tc)
        o[ti][tc] = __builtin_amdgcn_mfma_f32_16x16x32_bf16(pa[ti], vf[tc], o[ti][tc], 0, 0, 0);
  }

#pragma unroll
  for (int ti = 0; ti < 4; ++ti){
#pragma unroll
    for (int tc = 0; tc < 2; ++tc){
#pragma unroll
      for (int r = 0; r < 4; ++r){
        const int i = ti*16 + lg*4 + r;
        if (i < 49)
          outp[((size_t)win*49 + i)*512 + h*32 + tc*16 + lc] = f2bf(o[ti][tc][r]);
      }
    }
  }
}

// ---------------- LN kernels ----------------
// V=0: legacy — writes xout f32 AND x2 bf16.  V=1: writes x2 bf16 only.
template<int V>
__global__ __launch_bounds__(256) void ln1_kernel(const u16* __restrict__ xb,
      const u16* __restrict__ y, const float* __restrict__ g, const float* __restrict__ bt,
      float* __restrict__ xout, u16* __restrict__ xbf)
{
  __shared__ float red[8];
  const int t = blockIdx.x;
  const int b = t / 3136, s = t % 3136;
  const int hh = s / 56, ww2 = s % 56;
  int ph = hh + 53; if (ph >= 56) ph -= 56;
  int pw = ww2 + 53; if (pw >= 56) pw -= 56;
  const int win = b*64 + (ph/7)*8 + (pw/7);
  const int n   = (ph%7)*7 + (pw%7);
  const u16* yr = y + ((size_t)win*49 + n)*512;
  const int c = threadIdx.x * 2;
  u32 u = *(const u32*)(yr + c);
  float vx = bf2f((u16)(u & 0xffff)), vy = bf2f((u16)(u >> 16));
  float sum = vx + vy, sq = vx*vx + vy*vy;
#pragma unroll
  for (int off = 32; off; off >>= 1){ sum += __shfl_xor(sum, off); sq += __shfl_xor(sq, off); }
  if ((threadIdx.x & 63) == 0){ red[threadIdx.x >> 6] = sum; red[(threadIdx.x >> 6) + 4] = sq; }
  __syncthreads();
  sum = red[0]+red[1]+red[2]+red[3];
  sq  = red[4]+red[5]+red[6]+red[7];
  const float mu  = sum * (1.f/512.f);
  const float inv = rsqrtf(fmaxf(sq * (1.f/512.f) - mu*mu, 0.f) + 1e-5f);
  u32 ux = *(const u32*)(xb + (size_t)t*512 + c);
  float o0 = bf2f((u16)(ux & 0xffff)) + (vx - mu)*inv*g[c]   + bt[c];
  float o1 = bf2f((u16)(ux >> 16))    + (vy - mu)*inv*g[c+1] + bt[c+1];
  if (V == 0){
    float* orow = xout + (size_t)t*512;
    orow[c] = o0; orow[c+1] = o1;
  }
  *(u32*)(xbf + (size_t)t*512 + c) = (u32)f2bf(o0) | ((u32)f2bf(o1) << 16);
}

// V=0: out += LN(m) (RMW on f32 out).  V=1: out = x2bf + LN(m) (single write).
template<int V>
__global__ __launch_bounds__(256) void ln2_kernel(const u16* __restrict__ m,
      const u16* __restrict__ x2b, const float* __restrict__ g,
      const float* __restrict__ bt, float* __restrict__ out)
{
  __shared__ float red[8];
  const int t = blockIdx.x;
  const int c = threadIdx.x * 2;
  u32 u = *(const u32*)(m + (size_t)t*512 + c);
  float v0 = bf2f((u16)(u & 0xffff)), v1 = bf2f((u16)(u >> 16));
  float sum = v0 + v1, sq = v0*v0 + v1*v1;
#pragma unroll
  for (int off = 32; off; off >>= 1){ sum += __shfl_xor(sum, off); sq += __shfl_xor(sq, off); }
  if ((threadIdx.x & 63) == 0){ red[threadIdx.x >> 6] = sum; red[(threadIdx.x >> 6) + 4] = sq; }
  __syncthreads();
  sum = red[0]+red[1]+red[2]+red[3];
  sq  = red[4]+red[5]+red[6]+red[7];
  const float mu  = sum * (1.f/512.f);
  const float inv = rsqrtf(fmaxf(sq * (1.f/512.f) - mu*mu, 0.f) + 1e-5f);
  float* orow = out + (size_t)t*512;
  float a0 = (v0 - mu)*inv*g[c]   + bt[c];
  float a1 = (v1 - mu)*inv*g[c+1] + bt[c+1];
  if (V == 1){
    u32 ux = *(const u32*)(x2b + (size_t)t*512 + c);
    orow[c]   = bf2f((u16)(ux & 0xffff)) + a0;
    orow[c+1] = bf2f((u16)(ux >> 16))    + a1;
  } else {
    orow[c]   += a0;
    orow[c+1] += a1;
  }
}

// ---------------- tiny prep kernels ----------------
__global__ void cast_bf16_kernel(const float* __restrict__ in, u16* __restrict__ out, int n4){
  int i = blockIdx.x*256 + threadIdx.x;
  if (i >= n4) return;
  float4 v = *(const float4*)(in + (size_t)i*4);
  u32 lo = (u32)f2bf(v.x) | ((u32)f2bf(v.y) << 16);
  u32 hi = (u32)f2bf(v.z) | ((u32)f2bf(v.w) << 16);
  *(uint2*)(out + (size_t)i*4) = make_uint2(lo, hi);
}
__global__ void qkvbias_kernel(const float* __restrict__ qb, const float* __restrict__ vb,
                               float* __restrict__ out){
  int i = blockIdx.x*256 + threadIdx.x;
  if (i >= 1536) return;
  out[i] = i < 512 ? qb[i] : (i < 1024 ? 0.f : vb[i - 1024]);
}
__device__ __forceinline__ float cpb_coord(int d){
  float v = (float)(d - 6) * (8.f/6.f);
  float m = log2f(fabsf(v) + 1.f) * (1.f/3.f);
  return v > 0.f ? m : (v < 0.f ? -m : 0.f);
}
__global__ void cpb_kernel(const float* __restrict__ w1, const float* __restrict__ b1,
                           const float* __restrict__ w2, float* __restrict__ btbl){
  int idx = blockIdx.x*256 + threadIdx.x;
  if (idx >= 169*16) return;
  int e = idx >> 4, h = idx & 15;
  float t0 = cpb_coord(e / 13), t1 = cpb_coord(e % 13);
  float acc = 0.f;
  for (int jj = 0; jj < 512; ++jj){
    float hid = fmaxf(t0*w1[jj*2] + t1*w1[jj*2+1] + b1[jj], 0.f);
    acc += hid * w2[h*512 + jj];
  }
  btbl[e*16 + h] = acc;
}
__global__ void rpb_kernel(const float* __restrict__ btbl, float* __restrict__ rpb){
  int idx = blockIdx.x*256 + threadIdx.x;
  if (idx >= 16*49*49) return;
  int hh = idx / 2401, ij = idx % 2401, i = ij / 49, j = ij % 49;
  int dr = i/7 - j/7 + 6, dc = i%7 - j%7 + 6;
  float bb = btbl[(dr*13 + dc)*16 + hh];
  rpb[idx] = 16.f / (1.f + __expf(-bb));
}

// ---------------- launch ----------------
extern "C" void kernel_launch(void* const* d_in, const int* in_sizes, int n_in,
                              void* d_out, int out_size, void* d_ws, size_t ws_size,
                              hipStream_t stream)
{
  const float* x    = (const float*)d_in[0];
  const float* qkvw = (const float*)d_in[1];
  const float* qb   = (const float*)d_in[2];
  const float* vb   = (const float*)d_in[3];
  const float* ls   = (const float*)d_in[4];
  const float* cw1  = (const float*)d_in[5];
  const float* cb1  = (const float*)d_in[6];
  const float* cw2  = (const float*)d_in[7];
  const float* pw   = (const float*)d_in[8];
  const float* pb   = (const float*)d_in[9];
  const float* n1g  = (const float*)d_in[10];
  const float* n1b  = (const float*)d_in[11];
  const float* f1w  = (const float*)d_in[12];
  const float* f1b  = (const float*)d_in[13];
  const float* f2w  = (const float*)d_in[14];
  const float* f2b  = (const float*)d_in[15];
  const float* n2g  = (const float*)d_in[16];
  const float* n2b  = (const float*)d_in[17];

  char* ws = (char*)d_ws;
  const size_t SZ_BIG = (size_t)100352 * 2048 * 2;   // 411 MB big region
  const size_t SZ_MID = (size_t)100352 * 512  * 2;   // 103 MB mid region
  size_t o = SZ_BIG + SZ_MID;
  u16* wqkv  = (u16*)(ws + o); o += (size_t)1536*512*2;
  u16* wproj = (u16*)(ws + o); o += (size_t)512*512*2;
  u16* wfc1  = (u16*)(ws + o); o += (size_t)2048*512*2;
  u16* wfc2  = (u16*)(ws + o); o += (size_t)512*2048*2;
  float* qkvbias = (float*)(ws + o); o += 1536*4;
  float* btbl    = (float*)(ws + o); o += 2704*4;
  float* rpb     = (float*)(ws + o); o += 38416*4;

  // optional extra region for m (fc2 out) -- enables single-write d_out path
  u16* mreg = (u16*)(ws + o);
  const bool roomy = (ws_size >= o + SZ_MID);

  u16*   xbf   = (u16*)ws;
  u16*   qkvo  = (u16*)(ws + (size_t)100352*512*2);
  u16*   y_h   = qkvo;                    // reuses dead qkvo space
  u16*   big_h = (u16*)ws;
  u16*   mid   = (u16*)(ws + SZ_BIG);
  float* out   = (float*)d_out;

  cast_bf16_kernel<<<768,  256, 0, stream>>>(qkvw, wqkv, 1536*512/4);
  cast_bf16_kernel<<<256,  256, 0, stream>>>(pw,  wproj, 512*512/4);
  cast_bf16_kernel<<<1024, 256, 0, stream>>>(f1w, wfc1, 2048*512/4);
  cast_bf16_kernel<<<1024, 256, 0, stream>>>(f2w, wfc2, 512*2048/4);
  qkvbias_kernel<<<6, 256, 0, stream>>>(qb, vb, qkvbias);
  cpb_kernel<<<11, 256, 0, stream>>>(cw1, cb1, cw2, btbl);
  rpb_kernel<<<151, 256, 0, stream>>>(btbl, rpb);
  cast_bf16_kernel<<<50176, 256, 0, stream>>>(x, xbf, 100352*512/4);

  // QKV: row-gathered A (roll+window fused); 256x256 tiles, K=512 (NKT=16, BK=32)
  gemm_bt<0,2,16><<<392*6, 512, 0, stream>>>(xbf, wqkv, qkvbias,
                                             (void*)qkvo, 100352, 1536, 6);
  attn_mfma<<<8192, 256, 0, stream>>>(qkvo, rpb, ls, mid);
  // proj -> bf16 (window order); writes into dead qkv space
  gemm_bt<0,0,16><<<392*2, 512, 0, stream>>>(mid, wproj, pb,
                                             (void*)y_h, 100352, 512, 2);
  if (roomy){
    // x2bf only (no f32 residual round-trip)
    ln1_kernel<1><<<100352, 256, 0, stream>>>(xbf, y_h, n1g, n1b, out, mid);
    gemm_bt<2,0,16><<<392*8, 512, 0, stream>>>(mid, wfc1, f1b,
                                               (void*)big_h, 100352, 2048, 8);
    gemm_bt<0,0,64><<<392*2, 512, 0, stream>>>(big_h, wfc2, f2b,
                                               (void*)mreg, 100352, 512, 2);
    // out = x2bf + LN(m): single write of d_out
    ln2_kernel<1><<<100352, 256, 0, stream>>>(mreg, mid, n2g, n2b, out);
  } else {
    // legacy path: f32 residual in d_out, RMW in ln2
    ln1_kernel<0><<<100352, 256, 0, stream>>>(xbf, y_h, n1g, n1b, out, mid);
    gemm_bt<2,0,16><<<392*8, 512, 0, stream>>>(mid, wfc1, f1b,
                                               (void*)big_h, 100352, 2048, 8);
    gemm_bt<0,0,64><<<392*2, 512, 0, stream>>>(big_h, wfc2, f2b,
                                               (void*)mid, 100352, 512, 2);
    ln2_kernel<0><<<100352, 256, 0, stream>>>(mid, nullptr, n2g, n2b, out);
  }
}

// Round 16
// 1840.803 us; speedup vs baseline: 9.4159x; 9.4159x over previous
//
#include <hip/hip_runtime.h>

typedef unsigned short u16;
typedef unsigned int   u32;

using f32x4  = __attribute__((ext_vector_type(4))) float;
using bf16x8 = __attribute__((ext_vector_type(8))) short;  // 8 bf16 in 4 VGPRs

__device__ __forceinline__ float bf2f(u16 u){
  union { u32 i; float f; } x; x.i = ((u32)u) << 16; return x.f;
}
__device__ __forceinline__ u16 f2bf(float f){
  union { float f; u32 i; } x; x.f = f;
  u32 r = x.i + 0x7FFFu + ((x.i >> 16) & 1u);   // RNE
  return (u16)(r >> 16);
}
// tanh-form GELU, safe at +/-inf exp: tanh(u) = 1 - 2/(e^{2u}+1)
__device__ __forceinline__ float gelu_f(float v){
  float u = 0.7978845608f * v * (1.f + 0.044715f*v*v);
  float e = __expf(2.f*u);
  return 0.5f*v*(2.f - 2.f/(e + 1.f));
}

// async global->LDS, 16B per lane. LDS dest = wave-uniform base + lane*16 (HW);
// global source address is per-lane (enables row-gather + pre-swizzled staging).
__device__ __forceinline__ void glds16(const void* g, void* l){
  __builtin_amdgcn_global_load_lds(
      (const __attribute__((address_space(1))) unsigned int*)g,
      (__attribute__((address_space(3))) unsigned int*)(unsigned int)(unsigned long long)l,
      16, 0, 0);
}

// window-order token m -> source row in x (roll by -3,-3 then 7x7 window partition)
__device__ __forceinline__ int rollmap(int m){
  int win = m / 49, n = m % 49;
  int b  = win >> 6, wi = win & 63;
  int wh = wi >> 3, ww = wi & 7;
  int r = n / 7, c = n % 7;
  int sh = wh*7 + r + 3; if (sh >= 56) sh -= 56;
  int sw = ww*7 + c + 3; if (sw >= 56) sw -= 56;
  return b*3136 + sh*56 + sw;
}

// row-swizzled 16B-chunk offset within a [256 rows][32k] 64B-row region (R9-verified)
__device__ __forceinline__ int rowswz(int r, int ck){
  return ((r>>1)<<7) + (((((r&1)<<2)|ck) ^ ((r>>1)&7))<<4);
}

// ---------------- GEMM: C[M,N] = A[M,K] @ W[N,K]^T + bias ----------------
// BM=BN=256, BK=32; 512 thr / 8 waves (2Mx4N), per-wave 128x64 output.
// A: LDS 3 x 16KB ring (depth-2 stage via glds16, R9 pre-swizzle).
// B: DIRECT from global into registers (fb[4] = 4 x dwordx4, 16 cache lines
//    per instr, L2-hot), double-buffered fbA/fbB one tile ahead.
// LDS pipe now carries A only (~1030 cyc/tile/CU) < MFMA (~1240 cyc) -> the
// matrix pipe is finally the longest pipe even at 1 block/CU.
// Per tile: issue [4 fb loads, 2 stgA] -> 2 MFMA phases (lgkm-gated) ->
// vmcnt(2) (drains stgA(T+1)+fb(T+1), leaves stgA(T+2)) -> 1 barrier.
// NOTE: __launch_bounds__(512) only -- R15's (512,6) forced an 85-VGPR cap
// and spilled the whole accumulator to scratch (17 ms, VGPR=40, 19 GB HBM).
// AMODE 0: A row-major. AMODE 2: roll/window row-gather.
// EPI 0: bf16 out. EPI 2: bf16 out + GELU.
template<int EPI, int AMODE, int NKT>
__global__ __launch_bounds__(512) void gemm_bt(const u16* __restrict__ A,
      const u16* __restrict__ Bw, const float* __restrict__ bias,
      void* __restrict__ outp, int M, int N, int nbn)
{
  constexpr int K = NKT * 32;
  __shared__ __align__(16) char LDS[3*16384];   // 48 KB: A ring only
  const int t    = threadIdx.x;
  const int lane = t & 63, wave = t >> 6;
  const int wr = wave >> 2, wn = wave & 3;
  const int lr = lane & 15, lk = lane >> 4;

  // XCD-chunked block swizzle; bn fastest (A-panel shared by consecutive blocks).
  const int gl = ((blockIdx.x & 7) * ((int)gridDim.x >> 3)) + (blockIdx.x >> 3);
  const int bm = gl / nbn, bn = gl - bm*nbn;

  // ---- A staging source (pre-swizzled R9 formula) ----
  const int q   = (t & 7) ^ ((t >> 3) & 7);
  const int sr0 = 2*(t >> 3) + (q >> 2);
  const int sch = (q & 3) * 8;
  const u16 *pA0, *pA1;
  if constexpr (AMODE == 0){
    pA0 = A + (size_t)(bm*256 + sr0      )*K + sch;
    pA1 = A + (size_t)(bm*256 + sr0 + 128)*K + sch;
  } else {
    pA0 = A + (size_t)rollmap(bm*256 + sr0      )*K + sch;
    pA1 = A + (size_t)rollmap(bm*256 + sr0 + 128)*K + sch;
  }
  // ---- B-direct per-lane fragment bases ----
  const u16* pB[4];
#pragma unroll
  for (int j = 0; j < 4; ++j)
    pB[j] = Bw + (size_t)(bn*256 + wn*64 + j*16 + lr)*K + lk*8;

  int oA[8];
#pragma unroll
  for (int i = 0; i < 8; ++i) oA[i] = rowswz(wr*128 + i*16 + lr, lk);

  f32x4 acc[8][4];
#pragma unroll
  for (int i = 0; i < 8; ++i)
#pragma unroll
    for (int j = 0; j < 4; ++j) acc[i][j] = (f32x4){0.f, 0.f, 0.f, 0.f};

  auto stgA = [&](int T, int buf){
    char* d = LDS + buf*16384 + wave*1024;
    const int e = T*32;
    glds16(pA0 + e, d);
    glds16(pA1 + e, d + 8192);
  };
  auto ldB = [&](int T, bf16x8 (&fb)[4]){
#pragma unroll
    for (int j = 0; j < 4; ++j)
      fb[j] = *(const bf16x8*)(pB[j] + T*32);
  };

  bf16x8 fbA[4], fbB[4];

  // ---- prologue: fb(0) + A tiles 0,1 ----
  ldB(0, fbA);          // 4 loads (oldest)
  stgA(0, 0);           // 2
  stgA(1, 1);           // 2 (youngest)
  asm volatile("s_waitcnt vmcnt(2)" ::: "memory");   // fb0 + stgA0 done; stgA1 flies
  __builtin_amdgcn_s_barrier();
  asm volatile("" ::: "memory");

  auto TILE = [&](int T, int bcur, bf16x8 (&fbu)[4], bf16x8 (&fbl)[4]){
    if (T + 1 < NKT) ldB(T + 1, fbl);               // 4 vm loads (older)
    if (T + 2 < NKT){
      int bs = bcur + 2; if (bs >= 3) bs -= 3;
      stgA(T + 2, bs);                              // 2 vm loads (younger)
    }
    const char* ld = LDS + bcur*16384;
    bf16x8 fa[4];
#pragma unroll
    for (int i = 0; i < 4; ++i) fa[i] = *(const bf16x8*)(ld + oA[i]);
    asm volatile("s_waitcnt lgkmcnt(0)" ::: "memory");
    __builtin_amdgcn_sched_barrier(0);
    __builtin_amdgcn_s_setprio(1);
#pragma unroll
    for (int i = 0; i < 4; ++i)
#pragma unroll
      for (int j = 0; j < 4; ++j)
        acc[i][j] = __builtin_amdgcn_mfma_f32_16x16x32_bf16(fa[i], fbu[j], acc[i][j], 0, 0, 0);
    __builtin_amdgcn_s_setprio(0);
#pragma unroll
    for (int i = 0; i < 4; ++i) fa[i] = *(const bf16x8*)(ld + oA[4+i]);
    asm volatile("s_waitcnt lgkmcnt(0)" ::: "memory");
    __builtin_amdgcn_sched_barrier(0);
    __builtin_amdgcn_s_setprio(1);
#pragma unroll
    for (int i = 0; i < 4; ++i)
#pragma unroll
      for (int j = 0; j < 4; ++j)
        acc[4+i][j] = __builtin_amdgcn_mfma_f32_16x16x32_bf16(fa[i], fbu[j], acc[4+i][j], 0, 0, 0);
    __builtin_amdgcn_s_setprio(0);
    // drain: stgA(T+1) (issued last tile) + fb(T+1); stgA(T+2) stays in flight
    if (T + 2 < NKT)      asm volatile("s_waitcnt vmcnt(2)" ::: "memory");
    else if (T + 1 < NKT) asm volatile("s_waitcnt vmcnt(0)" ::: "memory");
    if (T + 1 < NKT){
      __builtin_amdgcn_s_barrier();
      asm volatile("" ::: "memory");
    }
  };

  int bcur = 0;
  for (int p = 0; p < NKT/2; ++p){
    TILE(2*p,     bcur, fbA, fbB);  bcur = (bcur == 2) ? 0 : bcur + 1;
    TILE(2*p + 1, bcur, fbB, fbA);  bcur = (bcur == 2) ? 0 : bcur + 1;
  }

  // ---- epilogue ----
  const int lc = lane & 15, lg = lane >> 4;
#pragma unroll
  for (int i = 0; i < 8; ++i){
#pragma unroll
    for (int j = 0; j < 4; ++j){
      int cm = bm*256 + wr*128 + i*16 + lg*4;
      int cn = bn*256 + wn*64  + j*16 + lc;
      float bv = bias[cn];
#pragma unroll
      for (int r = 0; r < 4; ++r){
        float v = acc[i][j][r] + bv;
        if (EPI == 2) v = gelu_f(v);
        ((u16*)outp)[(size_t)(cm + r)*N + cn] = f2bf(v);
      }
    }
  }
}

// ---------------- MFMA attention: 1 wave per (window, head), 4 waves/block ----
__global__ __launch_bounds__(256, 2) void attn_mfma(const u16* __restrict__ qkv,
      const float* __restrict__ rpb, const float* __restrict__ ls,
      u16* __restrict__ outp)
{
  __shared__ __align__(16) u16 Pl[4][64*72];
  __shared__ __align__(16) u16 Vl[4][32*72];
  __shared__ unsigned char regid[64];
  const int tid  = threadIdx.x, lane = tid & 63, wave = tid >> 6;
  const int lc = lane & 15, lg = lane >> 4;
  const int pair = blockIdx.x*4 + wave;
  const int win = pair >> 4, h = pair & 15;

  const u16* qb = qkv + (size_t)win*49*1536 + h*32;
  const u16* kb = qb + 512;
  const u16* vb = qb + 1024;

  if (tid < 49){
    int wi = win & 63, wh = wi >> 3, ww = wi & 7;
    int q7 = (tid*37) >> 8, r7 = tid - q7*7;
    int gh = wh*7 + q7, gw = ww*7 + r7;
    int rh = gh < 49 ? 0 : (gh < 53 ? 1 : 2);
    int rw = gw < 49 ? 0 : (gw < 53 ? 1 : 2);
    regid[tid] = (unsigned char)(rh*3 + rw);
  }

  u16* V = &Vl[wave][0];
#pragma unroll
  for (int it = 0; it < 4; ++it){
    int ch = it*64 + lane;
    int n = ch >> 2, oct = ch & 3;
    union { int4 i4; u16 s[8]; } v8;
    if (n < 49) v8.i4 = *(const int4*)(vb + (size_t)n*1536 + oct*8);
    else        v8.i4 = make_int4(0,0,0,0);
#pragma unroll
    for (int q = 0; q < 8; ++q) V[(oct*8 + q)*72 + n] = v8.s[q];
  }

  const float scale = __expf(fminf(ls[h], 4.6051702f));
  bf16x8 qf[4], kf[4];
#pragma unroll
  for (int ti = 0; ti < 4; ++ti){
    const int n = ti*16 + lc;
    {
      union { int4 i4; u16 s[8]; } raw;
      raw.i4 = *(const int4*)(qb + (size_t)n*1536 + lg*8);
      float f[8]; float ss = 0.f;
#pragma unroll
      for (int q = 0; q < 8; ++q){ f[q] = bf2f(raw.s[q]); ss += f[q]*f[q]; }
      ss += __shfl_xor(ss, 16); ss += __shfl_xor(ss, 32);
      const float inv = scale / fmaxf(sqrtf(ss), 1e-12f);
      union { short s[8]; bf16x8 v; } o;
#pragma unroll
      for (int q = 0; q < 8; ++q) o.s[q] = (short)f2bf(f[q]*inv);
      qf[ti] = o.v;
    }
    {
      union { int4 i4; u16 s[8]; } raw;
      raw.i4 = *(const int4*)(kb + (size_t)n*1536 + lg*8);
      float f[8]; float ss = 0.f;
#pragma unroll
      for (int q = 0; q < 8; ++q){ f[q] = bf2f(raw.s[q]); ss += f[q]*f[q]; }
      ss += __shfl_xor(ss, 16); ss += __shfl_xor(ss, 32);
      const float inv = 1.f / fmaxf(sqrtf(ss), 1e-12f);
      union { short s[8]; bf16x8 v; } o;
#pragma unroll
      for (int q = 0; q < 8; ++q) o.s[q] = (short)f2bf(f[q]*inv);
      kf[ti] = o.v;
    }
  }
  __syncthreads();

  f32x4 acc[4][4];
#pragma unroll
  for (int i = 0; i < 4; ++i)
#pragma unroll
    for (int j = 0; j < 4; ++j) acc[i][j] = (f32x4){0.f,0.f,0.f,0.f};
#pragma unroll
  for (int i = 0; i < 4; ++i)
#pragma unroll
    for (int j = 0; j < 4; ++j)
      acc[i][j] = __builtin_amdgcn_mfma_f32_16x16x32_bf16(qf[i], kf[j], acc[i][j], 0, 0, 0);

  u16* P = &Pl[wave][0];
  int rj[4];
#pragma unroll
  for (int tj = 0; tj < 4; ++tj){
    int j = tj*16 + lc;
    rj[tj] = (int)regid[j < 49 ? j : 0];
  }
  const float* rpbh = rpb + h*2401;
#pragma unroll
  for (int ti = 0; ti < 4; ++ti){
#pragma unroll
    for (int r = 0; r < 4; ++r){
      const int i = ti*16 + lg*4 + r;
      const bool iv = i < 49;
      const int ic = iv ? i : 0;
      const int ri = (int)regid[ic];
      const float* rrow = rpbh + ic*49;
      float sv[4];
#pragma unroll
      for (int tj = 0; tj < 4; ++tj){
        const int j = tj*16 + lc;
        float t2 = acc[ti][tj][r] + rrow[j < 49 ? j : 0];
        if (ri != rj[tj]) t2 -= 100.f;
        sv[tj] = (iv && j < 49) ? t2 : -1e30f;
      }
      float mx = fmaxf(fmaxf(sv[0],sv[1]), fmaxf(sv[2],sv[3]));
      mx = fmaxf(mx, __shfl_xor(mx, 1));
      mx = fmaxf(mx, __shfl_xor(mx, 2));
      mx = fmaxf(mx, __shfl_xor(mx, 4));
      mx = fmaxf(mx, __shfl_xor(mx, 8));
      float p[4], sum = 0.f;
#pragma unroll
      for (int tj = 0; tj < 4; ++tj){ p[tj] = __expf(sv[tj] - mx); sum += p[tj]; }
      sum += __shfl_xor(sum, 1); sum += __shfl_xor(sum, 2);
      sum += __shfl_xor(sum, 4); sum += __shfl_xor(sum, 8);
      const float rs = __builtin_amdgcn_rcpf(sum);
#pragma unroll
      for (int tj = 0; tj < 4; ++tj) P[i*72 + tj*16 + lc] = f2bf(p[tj]*rs);
    }
  }
  __syncthreads();

  f32x4 o[4][2];
#pragma unroll
  for (int i = 0; i < 4; ++i){ o[i][0] = (f32x4){0.f,0.f,0.f,0.f}; o[i][1] = (f32x4){0.f,0.f,0.f,0.f}; }
#pragma unroll
  for (int ks = 0; ks < 2; ++ks){
    bf16x8 pa[4], vf[2];
#pragma unroll
    for (int ti = 0; ti < 4; ++ti)
      pa[ti] = *(const bf16x8*)((const char*)P + (ti*16 + lc)*144 + (ks*4 + lg)*16);
#pragma unroll
    for (int tc = 0; tc < 2; ++tc)
      vf[tc] = *(const bf16x8*)((const char*)V + (tc*16 + lc)*144 + (ks*4 + lg)*16);
#pragma unroll
    for (int ti = 0; ti < 4; ++ti)
#pragma unroll
      for (int tc = 0; tc < 2; ++tc)
        o[ti][tc] = __builtin_amdgcn_mfma_f32_16x16x32_bf16(pa[ti], vf[tc], o[ti][tc], 0, 0, 0);
  }

#pragma unroll
  for (int ti = 0; ti < 4; ++ti){
#pragma unroll
    for (int tc = 0; tc < 2; ++tc){
#pragma unroll
      for (int r = 0; r < 4; ++r){
        const int i = ti*16 + lg*4 + r;
        if (i < 49)
          outp[((size_t)win*49 + i)*512 + h*32 + tc*16 + lc] = f2bf(o[ti][tc][r]);
      }
    }
  }
}

// ---------------- LN kernels ----------------
// V=0: legacy — writes xout f32 AND x2 bf16.  V=1: writes x2 bf16 only.
template<int V>
__global__ __launch_bounds__(256) void ln1_kernel(const u16* __restrict__ xb,
      const u16* __restrict__ y, const float* __restrict__ g, const float* __restrict__ bt,
      float* __restrict__ xout, u16* __restrict__ xbf)
{
  __shared__ float red[8];
  const int t = blockIdx.x;
  const int b = t / 3136, s = t % 3136;
  const int hh = s / 56, ww2 = s % 56;
  int ph = hh + 53; if (ph >= 56) ph -= 56;
  int pw = ww2 + 53; if (pw >= 56) pw -= 56;
  const int win = b*64 + (ph/7)*8 + (pw/7);
  const int n   = (ph%7)*7 + (pw%7);
  const u16* yr = y + ((size_t)win*49 + n)*512;
  const int c = threadIdx.x * 2;
  u32 u = *(const u32*)(yr + c);
  float vx = bf2f((u16)(u & 0xffff)), vy = bf2f((u16)(u >> 16));
  float sum = vx + vy, sq = vx*vx + vy*vy;
#pragma unroll
  for (int off = 32; off; off >>= 1){ sum += __shfl_xor(sum, off); sq += __shfl_xor(sq, off); }
  if ((threadIdx.x & 63) == 0){ red[threadIdx.x >> 6] = sum; red[(threadIdx.x >> 6) + 4] = sq; }
  __syncthreads();
  sum = red[0]+red[1]+red[2]+red[3];
  sq  = red[4]+red[5]+red[6]+red[7];
  const float mu  = sum * (1.f/512.f);
  const float inv = rsqrtf(fmaxf(sq * (1.f/512.f) - mu*mu, 0.f) + 1e-5f);
  u32 ux = *(const u32*)(xb + (size_t)t*512 + c);
  float o0 = bf2f((u16)(ux & 0xffff)) + (vx - mu)*inv*g[c]   + bt[c];
  float o1 = bf2f((u16)(ux >> 16))    + (vy - mu)*inv*g[c+1] + bt[c+1];
  if (V == 0){
    float* orow = xout + (size_t)t*512;
    orow[c] = o0; orow[c+1] = o1;
  }
  *(u32*)(xbf + (size_t)t*512 + c) = (u32)f2bf(o0) | ((u32)f2bf(o1) << 16);
}

// V=0: out += LN(m) (RMW on f32 out).  V=1: out = x2bf + LN(m) (single write).
template<int V>
__global__ __launch_bounds__(256) void ln2_kernel(const u16* __restrict__ m,
      const u16* __restrict__ x2b, const float* __restrict__ g,
      const float* __restrict__ bt, float* __restrict__ out)
{
  __shared__ float red[8];
  const int t = blockIdx.x;
  const int c = threadIdx.x * 2;
  u32 u = *(const u32*)(m + (size_t)t*512 + c);
  float v0 = bf2f((u16)(u & 0xffff)), v1 = bf2f((u16)(u >> 16));
  float sum = v0 + v1, sq = v0*v0 + v1*v1;
#pragma unroll
  for (int off = 32; off; off >>= 1){ sum += __shfl_xor(sum, off); sq += __shfl_xor(sq, off); }
  if ((threadIdx.x & 63) == 0){ red[threadIdx.x >> 6] = sum; red[(threadIdx.x >> 6) + 4] = sq; }
  __syncthreads();
  sum = red[0]+red[1]+red[2]+red[3];
  sq  = red[4]+red[5]+red[6]+red[7];
  const float mu  = sum * (1.f/512.f);
  const float inv = rsqrtf(fmaxf(sq * (1.f/512.f) - mu*mu, 0.f) + 1e-5f);
  float* orow = out + (size_t)t*512;
  float a0 = (v0 - mu)*inv*g[c]   + bt[c];
  float a1 = (v1 - mu)*inv*g[c+1] + bt[c+1];
  if (V == 1){
    u32 ux = *(const u32*)(x2b + (size_t)t*512 + c);
    orow[c]   = bf2f((u16)(ux & 0xffff)) + a0;
    orow[c+1] = bf2f((u16)(ux >> 16))    + a1;
  } else {
    orow[c]   += a0;
    orow[c+1] += a1;
  }
}

// ---------------- tiny prep kernels ----------------
__global__ void cast_bf16_kernel(const float* __restrict__ in, u16* __restrict__ out, int n4){
  int i = blockIdx.x*256 + threadIdx.x;
  if (i >= n4) return;
  float4 v = *(const float4*)(in + (size_t)i*4);
  u32 lo = (u32)f2bf(v.x) | ((u32)f2bf(v.y) << 16);
  u32 hi = (u32)f2bf(v.z) | ((u32)f2bf(v.w) << 16);
  *(uint2*)(out + (size_t)i*4) = make_uint2(lo, hi);
}
__global__ void qkvbias_kernel(const float* __restrict__ qb, const float* __restrict__ vb,
                               float* __restrict__ out){
  int i = blockIdx.x*256 + threadIdx.x;
  if (i >= 1536) return;
  out[i] = i < 512 ? qb[i] : (i < 1024 ? 0.f : vb[i - 1024]);
}
__device__ __forceinline__ float cpb_coord(int d){
  float v = (float)(d - 6) * (8.f/6.f);
  float m = log2f(fabsf(v) + 1.f) * (1.f/3.f);
  return v > 0.f ? m : (v < 0.f ? -m : 0.f);
}
__global__ void cpb_kernel(const float* __restrict__ w1, const float* __restrict__ b1,
                           const float* __restrict__ w2, float* __restrict__ btbl){
  int idx = blockIdx.x*256 + threadIdx.x;
  if (idx >= 169*16) return;
  int e = idx >> 4, h = idx & 15;
  float t0 = cpb_coord(e / 13), t1 = cpb_coord(e % 13);
  float acc = 0.f;
  for (int jj = 0; jj < 512; ++jj){
    float hid = fmaxf(t0*w1[jj*2] + t1*w1[jj*2+1] + b1[jj], 0.f);
    acc += hid * w2[h*512 + jj];
  }
  btbl[e*16 + h] = acc;
}
__global__ void rpb_kernel(const float* __restrict__ btbl, float* __restrict__ rpb){
  int idx = blockIdx.x*256 + threadIdx.x;
  if (idx >= 16*49*49) return;
  int hh = idx / 2401, ij = idx % 2401, i = ij / 49, j = ij % 49;
  int dr = i/7 - j/7 + 6, dc = i%7 - j%7 + 6;
  float bb = btbl[(dr*13 + dc)*16 + hh];
  rpb[idx] = 16.f / (1.f + __expf(-bb));
}

// ---------------- launch ----------------
extern "C" void kernel_launch(void* const* d_in, const int* in_sizes, int n_in,
                              void* d_out, int out_size, void* d_ws, size_t ws_size,
                              hipStream_t stream)
{
  const float* x    = (const float*)d_in[0];
  const float* qkvw = (const float*)d_in[1];
  const float* qb   = (const float*)d_in[2];
  const float* vb   = (const float*)d_in[3];
  const float* ls   = (const float*)d_in[4];
  const float* cw1  = (const float*)d_in[5];
  const float* cb1  = (const float*)d_in[6];
  const float* cw2  = (const float*)d_in[7];
  const float* pw   = (const float*)d_in[8];
  const float* pb   = (const float*)d_in[9];
  const float* n1g  = (const float*)d_in[10];
  const float* n1b  = (const float*)d_in[11];
  const float* f1w  = (const float*)d_in[12];
  const float* f1b  = (const float*)d_in[13];
  const float* f2w  = (const float*)d_in[14];
  const float* f2b  = (const float*)d_in[15];
  const float* n2g  = (const float*)d_in[16];
  const float* n2b  = (const float*)d_in[17];

  char* ws = (char*)d_ws;
  const size_t SZ_BIG = (size_t)100352 * 2048 * 2;   // 411 MB big region
  const size_t SZ_MID = (size_t)100352 * 512  * 2;   // 103 MB mid region
  size_t o = SZ_BIG + SZ_MID;
  u16* wqkv  = (u16*)(ws + o); o += (size_t)1536*512*2;
  u16* wproj = (u16*)(ws + o); o += (size_t)512*512*2;
  u16* wfc1  = (u16*)(ws + o); o += (size_t)2048*512*2;
  u16* wfc2  = (u16*)(ws + o); o += (size_t)512*2048*2;
  float* qkvbias = (float*)(ws + o); o += 1536*4;
  float* btbl    = (float*)(ws + o); o += 2704*4;
  float* rpb     = (float*)(ws + o); o += 38416*4;

  // optional extra region for m (fc2 out) -- enables single-write d_out path
  u16* mreg = (u16*)(ws + o);
  const bool roomy = (ws_size >= o + SZ_MID);

  u16*   xbf   = (u16*)ws;
  u16*   qkvo  = (u16*)(ws + (size_t)100352*512*2);
  u16*   y_h   = qkvo;                    // reuses dead qkvo space
  u16*   big_h = (u16*)ws;
  u16*   mid   = (u16*)(ws + SZ_BIG);
  float* out   = (float*)d_out;

  cast_bf16_kernel<<<768,  256, 0, stream>>>(qkvw, wqkv, 1536*512/4);
  cast_bf16_kernel<<<256,  256, 0, stream>>>(pw,  wproj, 512*512/4);
  cast_bf16_kernel<<<1024, 256, 0, stream>>>(f1w, wfc1, 2048*512/4);
  cast_bf16_kernel<<<1024, 256, 0, stream>>>(f2w, wfc2, 512*2048/4);
  qkvbias_kernel<<<6, 256, 0, stream>>>(qb, vb, qkvbias);
  cpb_kernel<<<11, 256, 0, stream>>>(cw1, cb1, cw2, btbl);
  rpb_kernel<<<151, 256, 0, stream>>>(btbl, rpb);
  cast_bf16_kernel<<<50176, 256, 0, stream>>>(x, xbf, 100352*512/4);

  // QKV: row-gathered A (roll+window fused); 256x256 tiles, K=512 (NKT=16, BK=32)
  gemm_bt<0,2,16><<<392*6, 512, 0, stream>>>(xbf, wqkv, qkvbias,
                                             (void*)qkvo, 100352, 1536, 6);
  attn_mfma<<<8192, 256, 0, stream>>>(qkvo, rpb, ls, mid);
  // proj -> bf16 (window order); writes into dead qkv space
  gemm_bt<0,0,16><<<392*2, 512, 0, stream>>>(mid, wproj, pb,
                                             (void*)y_h, 100352, 512, 2);
  if (roomy){
    // x2bf only (no f32 residual round-trip)
    ln1_kernel<1><<<100352, 256, 0, stream>>>(xbf, y_h, n1g, n1b, out, mid);
    gemm_bt<2,0,16><<<392*8, 512, 0, stream>>>(mid, wfc1, f1b,
                                               (void*)big_h, 100352, 2048, 8);
    gemm_bt<0,0,64><<<392*2, 512, 0, stream>>>(big_h, wfc2, f2b,
                                               (void*)mreg, 100352, 512, 2);
    // out = x2bf + LN(m): single write of d_out
    ln2_kernel<1><<<100352, 256, 0, stream>>>(mreg, mid, n2g, n2b, out);
  } else {
    // legacy path: f32 residual in d_out, RMW in ln2
    ln1_kernel<0><<<100352, 256, 0, stream>>>(xbf, y_h, n1g, n1b, out, mid);
    gemm_bt<2,0,16><<<392*8, 512, 0, stream>>>(mid, wfc1, f1b,
                                               (void*)big_h, 100352, 2048, 8);
    gemm_bt<0,0,64><<<392*2, 512, 0, stream>>>(big_h, wfc2, f2b,
                                               (void*)mid, 100352, 512, 2);
    ln2_kernel<0><<<100352, 256, 0, stream>>>(mid, nullptr, n2g, n2b, out);
  }
}

// Round 17
// 1415.249 us; speedup vs baseline: 12.2472x; 1.3007x over previous
//
#include <hip/hip_runtime.h>

typedef unsigned short u16;
typedef unsigned int   u32;

using f32x4  = __attribute__((ext_vector_type(4))) float;
using bf16x8 = __attribute__((ext_vector_type(8))) short;  // 8 bf16 in 4 VGPRs

__device__ __forceinline__ float bf2f(u16 u){
  union { u32 i; float f; } x; x.i = ((u32)u) << 16; return x.f;
}
__device__ __forceinline__ u16 f2bf(float f){
  union { float f; u32 i; } x; x.f = f;
  u32 r = x.i + 0x7FFFu + ((x.i >> 16) & 1u);   // RNE
  return (u16)(r >> 16);
}
// tanh-form GELU, safe at +/-inf exp: tanh(u) = 1 - 2/(e^{2u}+1)
__device__ __forceinline__ float gelu_f(float v){
  float u = 0.7978845608f * v * (1.f + 0.044715f*v*v);
  float e = __expf(2.f*u);
  return 0.5f*v*(2.f - 2.f/(e + 1.f));
}

// async global->LDS, 16B per lane. LDS dest = wave-uniform base + lane*16 (HW);
// global source address is per-lane (enables row-gather + pre-swizzled staging).
__device__ __forceinline__ void glds16(const void* g, void* l){
  __builtin_amdgcn_global_load_lds(
      (const __attribute__((address_space(1))) unsigned int*)g,
      (__attribute__((address_space(3))) unsigned int*)(unsigned int)(unsigned long long)l,
      16, 0, 0);
}

// window-order token m -> source row in x (roll by -3,-3 then 7x7 window partition)
__device__ __forceinline__ int rollmap(int m){
  int win = m / 49, n = m % 49;
  int b  = win >> 6, wi = win & 63;
  int wh = wi >> 3, ww = wi & 7;
  int r = n / 7, c = n % 7;
  int sh = wh*7 + r + 3; if (sh >= 56) sh -= 56;
  int sw = ww*7 + c + 3; if (sw >= 56) sw -= 56;
  return b*3136 + sh*56 + sw;
}

// row-swizzled 16B-chunk offset within a [256 rows][32k] 64B-row region (R9-verified)
__device__ __forceinline__ int rowswz(int r, int ck){
  return ((r>>1)<<7) + (((((r&1)<<2)|ck) ^ ((r>>1)&7))<<4);
}

// ---------------- GEMM (R9 structure): C[M,N] = A[M,K] @ W[N,K]^T + bias ----
// BM=BN=256, BK=64, 512 thr / 8 waves (2Mx4N), per-wave 128x64 output.
// LDS 2 x 64KB dbuf; 4 ks-major 16KB regions [A0|A1|B0|B1]; pre-swizzled
// staging source; 4 phases/K-tile with counted vmcnt (never 0 in steady state).
// Best-measured GEMM structure of the session (R14 = 1415 us total).
template<int EPI, int AMODE, int NKT>
__global__ __launch_bounds__(512, 2) void gemm_bt(const u16* __restrict__ A,
      const u16* __restrict__ Bw, const float* __restrict__ bias,
      void* __restrict__ outp, int M, int N, int nbn)
{
  constexpr int K = NKT * 64;
  __shared__ __align__(16) char LDS[2*65536];   // 128 KB
  const int t    = threadIdx.x;
  const int lane = t & 63, wave = t >> 6;
  const int wr = wave >> 2, wn = wave & 3;
  const int lr = lane & 15, lk = lane >> 4;

  const int gl = ((blockIdx.x & 7) * ((int)gridDim.x >> 3)) + (blockIdx.x >> 3);
  const int bm = gl / nbn, bn = gl - bm*nbn;

  const int q   = (t & 7) ^ ((t >> 3) & 7);
  const int sr0 = 2*(t >> 3) + (q >> 2);
  const int sch = (q & 3) * 8;
  const u16 *pA0, *pA1;
  if constexpr (AMODE == 0){
    pA0 = A + (size_t)(bm*256 + sr0      )*K + sch;
    pA1 = A + (size_t)(bm*256 + sr0 + 128)*K + sch;
  } else {
    pA0 = A + (size_t)rollmap(bm*256 + sr0      )*K + sch;
    pA1 = A + (size_t)rollmap(bm*256 + sr0 + 128)*K + sch;
  }
  const u16* pB0 = Bw + (size_t)(bn*256 + sr0      )*K + sch;
  const u16* pB1 = Bw + (size_t)(bn*256 + sr0 + 128)*K + sch;

  int oA[8], oB[4];
#pragma unroll
  for (int i = 0; i < 8; ++i) oA[i] = rowswz(wr*128 + i*16 + lr, lk);
#pragma unroll
  for (int j = 0; j < 4; ++j) oB[j] = rowswz(wn*64 + j*16 + lr, lk);

  f32x4 acc[8][4];
#pragma unroll
  for (int i = 0; i < 8; ++i)
#pragma unroll
    for (int j = 0; j < 4; ++j) acc[i][j] = (f32x4){0.f, 0.f, 0.f, 0.f};

  auto stgA = [&](int T, int ks, int buf){
    char* d = LDS + buf*65536 + ks*16384 + wave*1024;
    const int e = T*64 + ks*32;
    glds16(pA0 + e, d);
    glds16(pA1 + e, d + 8192);
  };
  auto stgB = [&](int T, int ks, int buf){
    char* d = LDS + buf*65536 + 32768 + ks*16384 + wave*1024;
    const int e = T*64 + ks*32;
    glds16(pB0 + e, d);
    glds16(pB1 + e, d + 8192);
  };

  stgA(0,0,0); stgA(0,1,0); stgB(0,0,0); stgB(0,1,0);
  stgA(1,0,1); stgA(1,1,1); stgB(1,0,1); stgB(1,1,1);
  asm volatile("s_waitcnt vmcnt(8)" ::: "memory");
  __builtin_amdgcn_s_barrier();
  asm volatile("" ::: "memory");

  auto TILE = [&](int T, int buf){
    const char* ld = LDS + buf*65536;
    const bool stP0  = (T >= 1) && (T+1 < NKT);
    const bool st123 = (T+2 < NKT);
    bf16x8 fa[4], fb[4];

#pragma unroll
    for (int j = 0; j < 4; ++j) fb[j] = *(const bf16x8*)(ld + 32768 + oB[j]);
#pragma unroll
    for (int i = 0; i < 4; ++i) fa[i] = *(const bf16x8*)(ld + oA[i]);
    if (stP0) stgA(T+1, 1, buf^1);
    __builtin_amdgcn_s_barrier();
    asm volatile("s_waitcnt lgkmcnt(0)" ::: "memory");
    __builtin_amdgcn_sched_barrier(0);
    __builtin_amdgcn_s_setprio(1);
#pragma unroll
    for (int i = 0; i < 4; ++i)
#pragma unroll
      for (int j = 0; j < 4; ++j)
        acc[i][j] = __builtin_amdgcn_mfma_f32_16x16x32_bf16(fa[i], fb[j], acc[i][j], 0, 0, 0);
    __builtin_amdgcn_s_setprio(0);
    __builtin_amdgcn_s_barrier();
    asm volatile("" ::: "memory");

#pragma unroll
    for (int i = 0; i < 4; ++i) fa[i] = *(const bf16x8*)(ld + oA[4+i]);
    if (st123) stgB(T+2, 0, buf);
    __builtin_amdgcn_s_barrier();
    asm volatile("s_waitcnt lgkmcnt(0)" ::: "memory");
    __builtin_amdgcn_sched_barrier(0);
    __builtin_amdgcn_s_setprio(1);
#pragma unroll
    for (int i = 0; i < 4; ++i)
#pragma unroll
      for (int j = 0; j < 4; ++j)
        acc[4+i][j] = __builtin_amdgcn_mfma_f32_16x16x32_bf16(fa[i], fb[j], acc[4+i][j], 0, 0, 0);
    __builtin_amdgcn_s_setprio(0);
    __builtin_amdgcn_s_barrier();
    asm volatile("" ::: "memory");

#pragma unroll
    for (int j = 0; j < 4; ++j) fb[j] = *(const bf16x8*)(ld + 49152 + oB[j]);
#pragma unroll
    for (int i = 0; i < 4; ++i) fa[i] = *(const bf16x8*)(ld + 16384 + oA[i]);
    if (st123) stgA(T+2, 0, buf);
    __builtin_amdgcn_s_barrier();
    asm volatile("s_waitcnt lgkmcnt(0)" ::: "memory");
    __builtin_amdgcn_sched_barrier(0);
    __builtin_amdgcn_s_setprio(1);
#pragma unroll
    for (int i = 0; i < 4; ++i)
#pragma unroll
      for (int j = 0; j < 4; ++j)
        acc[i][j] = __builtin_amdgcn_mfma_f32_16x16x32_bf16(fa[i], fb[j], acc[i][j], 0, 0, 0);
    __builtin_amdgcn_s_setprio(0);
    __builtin_amdgcn_s_barrier();
    asm volatile("" ::: "memory");

#pragma unroll
    for (int i = 0; i < 4; ++i) fa[i] = *(const bf16x8*)(ld + 16384 + oA[4+i]);
    if (st123) stgB(T+2, 1, buf);
    __builtin_amdgcn_s_barrier();
    asm volatile("s_waitcnt lgkmcnt(0)" ::: "memory");
    __builtin_amdgcn_sched_barrier(0);
    __builtin_amdgcn_s_setprio(1);
#pragma unroll
    for (int i = 0; i < 4; ++i)
#pragma unroll
      for (int j = 0; j < 4; ++j)
        acc[4+i][j] = __builtin_amdgcn_mfma_f32_16x16x32_bf16(fa[i], fb[j], acc[4+i][j], 0, 0, 0);
    __builtin_amdgcn_s_setprio(0);
    if (T <= NKT-3)      asm volatile("s_waitcnt vmcnt(6)" ::: "memory");
    else if (T == NKT-2) asm volatile("s_waitcnt vmcnt(0)" ::: "memory");
    if (T < NKT-1){
      __builtin_amdgcn_s_barrier();
      asm volatile("" ::: "memory");
    }
  };

  for (int p = 0; p < NKT/2; ++p){
    TILE(2*p,     0);
    TILE(2*p + 1, 1);
  }

  const int lc = lane & 15, lg = lane >> 4;
#pragma unroll
  for (int i = 0; i < 8; ++i){
#pragma unroll
    for (int j = 0; j < 4; ++j){
      int cm = bm*256 + wr*128 + i*16 + lg*4;
      int cn = bn*256 + wn*64  + j*16 + lc;
      float bv = bias[cn];
#pragma unroll
      for (int r = 0; r < 4; ++r){
        float v = acc[i][j][r] + bv;
        if (EPI == 2) v = gelu_f(v);
        ((u16*)outp)[(size_t)(cm + r)*N + cn] = f2bf(v);
      }
    }
  }
}

// ---------------- MFMA attention: 1 wave per (window, head), 4 waves/block ----
__global__ __launch_bounds__(256, 2) void attn_mfma(const u16* __restrict__ qkv,
      const float* __restrict__ rpb, const float* __restrict__ ls,
      u16* __restrict__ outp)
{
  __shared__ __align__(16) u16 Pl[4][64*72];
  __shared__ __align__(16) u16 Vl[4][32*72];
  __shared__ unsigned char regid[64];
  const int tid  = threadIdx.x, lane = tid & 63, wave = tid >> 6;
  const int lc = lane & 15, lg = lane >> 4;
  const int pair = blockIdx.x*4 + wave;
  const int win = pair >> 4, h = pair & 15;

  const u16* qb = qkv + (size_t)win*49*1536 + h*32;
  const u16* kb = qb + 512;
  const u16* vb = qb + 1024;

  if (tid < 49){
    int wi = win & 63, wh = wi >> 3, ww = wi & 7;
    int q7 = (tid*37) >> 8, r7 = tid - q7*7;
    int gh = wh*7 + q7, gw = ww*7 + r7;
    int rh = gh < 49 ? 0 : (gh < 53 ? 1 : 2);
    int rw = gw < 49 ? 0 : (gw < 53 ? 1 : 2);
    regid[tid] = (unsigned char)(rh*3 + rw);
  }

  u16* V = &Vl[wave][0];
#pragma unroll
  for (int it = 0; it < 4; ++it){
    int ch = it*64 + lane;
    int n = ch >> 2, oct = ch & 3;
    union { int4 i4; u16 s[8]; } v8;
    if (n < 49) v8.i4 = *(const int4*)(vb + (size_t)n*1536 + oct*8);
    else        v8.i4 = make_int4(0,0,0,0);
#pragma unroll
    for (int q = 0; q < 8; ++q) V[(oct*8 + q)*72 + n] = v8.s[q];
  }

  const float scale = __expf(fminf(ls[h], 4.6051702f));
  bf16x8 qf[4], kf[4];
#pragma unroll
  for (int ti = 0; ti < 4; ++ti){
    const int n = ti*16 + lc;
    {
      union { int4 i4; u16 s[8]; } raw;
      raw.i4 = *(const int4*)(qb + (size_t)n*1536 + lg*8);
      float f[8]; float ss = 0.f;
#pragma unroll
      for (int q = 0; q < 8; ++q){ f[q] = bf2f(raw.s[q]); ss += f[q]*f[q]; }
      ss += __shfl_xor(ss, 16); ss += __shfl_xor(ss, 32);
      const float inv = scale / fmaxf(sqrtf(ss), 1e-12f);
      union { short s[8]; bf16x8 v; } o;
#pragma unroll
      for (int q = 0; q < 8; ++q) o.s[q] = (short)f2bf(f[q]*inv);
      qf[ti] = o.v;
    }
    {
      union { int4 i4; u16 s[8]; } raw;
      raw.i4 = *(const int4*)(kb + (size_t)n*1536 + lg*8);
      float f[8]; float ss = 0.f;
#pragma unroll
      for (int q = 0; q < 8; ++q){ f[q] = bf2f(raw.s[q]); ss += f[q]*f[q]; }
      ss += __shfl_xor(ss, 16); ss += __shfl_xor(ss, 32);
      const float inv = 1.f / fmaxf(sqrtf(ss), 1e-12f);
      union { short s[8]; bf16x8 v; } o;
#pragma unroll
      for (int q = 0; q < 8; ++q) o.s[q] = (short)f2bf(f[q]*inv);
      kf[ti] = o.v;
    }
  }
  __syncthreads();

  f32x4 acc[4][4];
#pragma unroll
  for (int i = 0; i < 4; ++i)
#pragma unroll
    for (int j = 0; j < 4; ++j) acc[i][j] = (f32x4){0.f,0.f,0.f,0.f};
#pragma unroll
  for (int i = 0; i < 4; ++i)
#pragma unroll
    for (int j = 0; j < 4; ++j)
      acc[i][j] = __builtin_amdgcn_mfma_f32_16x16x32_bf16(qf[i], kf[j], acc[i][j], 0, 0, 0);

  u16* P = &Pl[wave][0];
  int rj[4];
#pragma unroll
  for (int tj = 0; tj < 4; ++tj){
    int j = tj*16 + lc;
    rj[tj] = (int)regid[j < 49 ? j : 0];
  }
  const float* rpbh = rpb + h*2401;
#pragma unroll
  for (int ti = 0; ti < 4; ++ti){
#pragma unroll
    for (int r = 0; r < 4; ++r){
      const int i = ti*16 + lg*4 + r;
      const bool iv = i < 49;
      const int ic = iv ? i : 0;
      const int ri = (int)regid[ic];
      const float* rrow = rpbh + ic*49;
      float sv[4];
#pragma unroll
      for (int tj = 0; tj < 4; ++tj){
        const int j = tj*16 + lc;
        float t2 = acc[ti][tj][r] + rrow[j < 49 ? j : 0];
        if (ri != rj[tj]) t2 -= 100.f;
        sv[tj] = (iv && j < 49) ? t2 : -1e30f;
      }
      float mx = fmaxf(fmaxf(sv[0],sv[1]), fmaxf(sv[2],sv[3]));
      mx = fmaxf(mx, __shfl_xor(mx, 1));
      mx = fmaxf(mx, __shfl_xor(mx, 2));
      mx = fmaxf(mx, __shfl_xor(mx, 4));
      mx = fmaxf(mx, __shfl_xor(mx, 8));
      float p[4], sum = 0.f;
#pragma unroll
      for (int tj = 0; tj < 4; ++tj){ p[tj] = __expf(sv[tj] - mx); sum += p[tj]; }
      sum += __shfl_xor(sum, 1); sum += __shfl_xor(sum, 2);
      sum += __shfl_xor(sum, 4); sum += __shfl_xor(sum, 8);
      const float rs = __builtin_amdgcn_rcpf(sum);
#pragma unroll
      for (int tj = 0; tj < 4; ++tj) P[i*72 + tj*16 + lc] = f2bf(p[tj]*rs);
    }
  }
  __syncthreads();

  f32x4 o[4][2];
#pragma unroll
  for (int i = 0; i < 4; ++i){ o[i][0] = (f32x4){0.f,0.f,0.f,0.f}; o[i][1] = (f32x4){0.f,0.f,0.f,0.f}; }
#pragma unroll
  for (int ks = 0; ks < 2; ++ks){
    bf16x8 pa[4], vf[2];
#pragma unroll
    for (int ti = 0; ti < 4; ++ti)
      pa[ti] = *(const bf16x8*)((const char*)P + (ti*16 + lc)*144 + (ks*4 + lg)*16);
#pragma unroll
    for (int tc = 0; tc < 2; ++tc)
      vf[tc] = *(const bf16x8*)((const char*)V + (tc*16 + lc)*144 + (ks*4 + lg)*16);
#pragma unroll
    for (int ti = 0; ti < 4; ++ti)
#pragma unroll
      for (int tc = 0; tc < 2; ++tc)
        o[ti][tc] = __builtin_amdgcn_mfma_f32_16x16x32_bf16(pa[ti], vf[tc], o[ti][tc], 0, 0, 0);
  }

#pragma unroll
  for (int ti = 0; ti < 4; ++ti){
#pragma unroll
    for (int tc = 0; tc < 2; ++tc){
#pragma unroll
      for (int r = 0; r < 4; ++r){
        const int i = ti*16 + lg*4 + r;
        if (i < 49)
          outp[((size_t)win*49 + i)*512 + h*32 + tc*16 + lc] = f2bf(o[ti][tc][r]);
      }
    }
  }
}

// ---------------- LN kernels ----------------
// V=0: legacy — writes xout f32 AND x2 bf16.  V=1: writes x2 bf16 only.
template<int V>
__global__ __launch_bounds__(256) void ln1_kernel(const u16* __restrict__ xb,
      const u16* __restrict__ y, const float* __restrict__ g, const float* __restrict__ bt,
      float* __restrict__ xout, u16* __restrict__ xbf)
{
  __shared__ float red[8];
  const int t = blockIdx.x;
  const int b = t / 3136, s = t % 3136;
  const int hh = s / 56, ww2 = s % 56;
  int ph = hh + 53; if (ph >= 56) ph -= 56;
  int pw = ww2 + 53; if (pw >= 56) pw -= 56;
  const int win = b*64 + (ph/7)*8 + (pw/7);
  const int n   = (ph%7)*7 + (pw%7);
  const u16* yr = y + ((size_t)win*49 + n)*512;
  const int c = threadIdx.x * 2;
  u32 u = *(const u32*)(yr + c);
  float vx = bf2f((u16)(u & 0xffff)), vy = bf2f((u16)(u >> 16));
  float sum = vx + vy, sq = vx*vx + vy*vy;
#pragma unroll
  for (int off = 32; off; off >>= 1){ sum += __shfl_xor(sum, off); sq += __shfl_xor(sq, off); }
  if ((threadIdx.x & 63) == 0){ red[threadIdx.x >> 6] = sum; red[(threadIdx.x >> 6) + 4] = sq; }
  __syncthreads();
  sum = red[0]+red[1]+red[2]+red[3];
  sq  = red[4]+red[5]+red[6]+red[7];
  const float mu  = sum * (1.f/512.f);
  const float inv = rsqrtf(fmaxf(sq * (1.f/512.f) - mu*mu, 0.f) + 1e-5f);
  u32 ux = *(const u32*)(xb + (size_t)t*512 + c);
  float o0 = bf2f((u16)(ux & 0xffff)) + (vx - mu)*inv*g[c]   + bt[c];
  float o1 = bf2f((u16)(ux >> 16))    + (vy - mu)*inv*g[c+1] + bt[c+1];
  if (V == 0){
    float* orow = xout + (size_t)t*512;
    orow[c] = o0; orow[c+1] = o1;
  }
  *(u32*)(xbf + (size_t)t*512 + c) = (u32)f2bf(o0) | ((u32)f2bf(o1) << 16);
}

// V=0: out += LN(m) (RMW on f32 out).  V=1: out = x2bf + LN(m) (single write).
template<int V>
__global__ __launch_bounds__(256) void ln2_kernel(const u16* __restrict__ m,
      const u16* __restrict__ x2b, const float* __restrict__ g,
      const float* __restrict__ bt, float* __restrict__ out)
{
  __shared__ float red[8];
  const int t = blockIdx.x;
  const int c = threadIdx.x * 2;
  u32 u = *(const u32*)(m + (size_t)t*512 + c);
  float v0 = bf2f((u16)(u & 0xffff)), v1 = bf2f((u16)(u >> 16));
  float sum = v0 + v1, sq = v0*v0 + v1*v1;
#pragma unroll
  for (int off = 32; off; off >>= 1){ sum += __shfl_xor(sum, off); sq += __shfl_xor(sq, off); }
  if ((threadIdx.x & 63) == 0){ red[threadIdx.x >> 6] = sum; red[(threadIdx.x >> 6) + 4] = sq; }
  __syncthreads();
  sum = red[0]+red[1]+red[2]+red[3];
  sq  = red[4]+red[5]+red[6]+red[7];
  const float mu  = sum * (1.f/512.f);
  const float inv = rsqrtf(fmaxf(sq * (1.f/512.f) - mu*mu, 0.f) + 1e-5f);
  float* orow = out + (size_t)t*512;
  float a0 = (v0 - mu)*inv*g[c]   + bt[c];
  float a1 = (v1 - mu)*inv*g[c+1] + bt[c+1];
  if (V == 1){
    u32 ux = *(const u32*)(x2b + (size_t)t*512 + c);
    orow[c]   = bf2f((u16)(ux & 0xffff)) + a0;
    orow[c+1] = bf2f((u16)(ux >> 16))    + a1;
  } else {
    orow[c]   += a0;
    orow[c+1] += a1;
  }
}

// ---------------- tiny prep kernels ----------------
__global__ void cast_bf16_kernel(const float* __restrict__ in, u16* __restrict__ out, int n4){
  int i = blockIdx.x*256 + threadIdx.x;
  if (i >= n4) return;
  float4 v = *(const float4*)(in + (size_t)i*4);
  u32 lo = (u32)f2bf(v.x) | ((u32)f2bf(v.y) << 16);
  u32 hi = (u32)f2bf(v.z) | ((u32)f2bf(v.w) << 16);
  *(uint2*)(out + (size_t)i*4) = make_uint2(lo, hi);
}
__global__ void qkvbias_kernel(const float* __restrict__ qb, const float* __restrict__ vb,
                               float* __restrict__ out){
  int i = blockIdx.x*256 + threadIdx.x;
  if (i >= 1536) return;
  out[i] = i < 512 ? qb[i] : (i < 1024 ? 0.f : vb[i - 1024]);
}
__device__ __forceinline__ float cpb_coord(int d){
  float v = (float)(d - 6) * (8.f/6.f);
  float m = log2f(fabsf(v) + 1.f) * (1.f/3.f);
  return v > 0.f ? m : (v < 0.f ? -m : 0.f);
}
__global__ void cpb_kernel(const float* __restrict__ w1, const float* __restrict__ b1,
                           const float* __restrict__ w2, float* __restrict__ btbl){
  int idx = blockIdx.x*256 + threadIdx.x;
  if (idx >= 169*16) return;
  int e = idx >> 4, h = idx & 15;
  float t0 = cpb_coord(e / 13), t1 = cpb_coord(e % 13);
  float acc = 0.f;
  for (int jj = 0; jj < 512; ++jj){
    float hid = fmaxf(t0*w1[jj*2] + t1*w1[jj*2+1] + b1[jj], 0.f);
    acc += hid * w2[h*512 + jj];
  }
  btbl[e*16 + h] = acc;
}
__global__ void rpb_kernel(const float* __restrict__ btbl, float* __restrict__ rpb){
  int idx = blockIdx.x*256 + threadIdx.x;
  if (idx >= 16*49*49) return;
  int hh = idx / 2401, ij = idx % 2401, i = ij / 49, j = ij % 49;
  int dr = i/7 - j/7 + 6, dc = i%7 - j%7 + 6;
  float bb = btbl[(dr*13 + dc)*16 + hh];
  rpb[idx] = 16.f / (1.f + __expf(-bb));
}

// ---------------- launch ----------------
extern "C" void kernel_launch(void* const* d_in, const int* in_sizes, int n_in,
                              void* d_out, int out_size, void* d_ws, size_t ws_size,
                              hipStream_t stream)
{
  const float* x    = (const float*)d_in[0];
  const float* qkvw = (const float*)d_in[1];
  const float* qb   = (const float*)d_in[2];
  const float* vb   = (const float*)d_in[3];
  const float* ls   = (const float*)d_in[4];
  const float* cw1  = (const float*)d_in[5];
  const float* cb1  = (const float*)d_in[6];
  const float* cw2  = (const float*)d_in[7];
  const float* pw   = (const float*)d_in[8];
  const float* pb   = (const float*)d_in[9];
  const float* n1g  = (const float*)d_in[10];
  const float* n1b  = (const float*)d_in[11];
  const float* f1w  = (const float*)d_in[12];
  const float* f1b  = (const float*)d_in[13];
  const float* f2w  = (const float*)d_in[14];
  const float* f2b  = (const float*)d_in[15];
  const float* n2g  = (const float*)d_in[16];
  const float* n2b  = (const float*)d_in[17];

  char* ws = (char*)d_ws;
  const size_t SZ_BIG = (size_t)100352 * 2048 * 2;   // 411 MB big region
  const size_t SZ_MID = (size_t)100352 * 512  * 2;   // 103 MB mid region
  size_t o = SZ_BIG + SZ_MID;
  u16* wqkv  = (u16*)(ws + o); o += (size_t)1536*512*2;
  u16* wproj = (u16*)(ws + o); o += (size_t)512*512*2;
  u16* wfc1  = (u16*)(ws + o); o += (size_t)2048*512*2;
  u16* wfc2  = (u16*)(ws + o); o += (size_t)512*2048*2;
  float* qkvbias = (float*)(ws + o); o += 1536*4;
  float* btbl    = (float*)(ws + o); o += 2704*4;
  float* rpb     = (float*)(ws + o); o += 38416*4;

  // optional extra region for m (fc2 out) -- enables single-write d_out path
  u16* mreg = (u16*)(ws + o);
  const bool roomy = (ws_size >= o + SZ_MID);

  u16*   xbf   = (u16*)ws;
  u16*   qkvo  = (u16*)(ws + (size_t)100352*512*2);
  u16*   y_h   = qkvo;                    // reuses dead qkvo space
  u16*   big_h = (u16*)ws;
  u16*   mid   = (u16*)(ws + SZ_BIG);
  float* out   = (float*)d_out;

  cast_bf16_kernel<<<768,  256, 0, stream>>>(qkvw, wqkv, 1536*512/4);
  cast_bf16_kernel<<<256,  256, 0, stream>>>(pw,  wproj, 512*512/4);
  cast_bf16_kernel<<<1024, 256, 0, stream>>>(f1w, wfc1, 2048*512/4);
  cast_bf16_kernel<<<1024, 256, 0, stream>>>(f2w, wfc2, 512*2048/4);
  qkvbias_kernel<<<6, 256, 0, stream>>>(qb, vb, qkvbias);
  cpb_kernel<<<11, 256, 0, stream>>>(cw1, cb1, cw2, btbl);
  rpb_kernel<<<151, 256, 0, stream>>>(btbl, rpb);
  cast_bf16_kernel<<<50176, 256, 0, stream>>>(x, xbf, 100352*512/4);

  // QKV: row-gathered A (roll+window fused); 256x256 tiles, K=512 (NKT=8)
  gemm_bt<0,2,8><<<392*6, 512, 0, stream>>>(xbf, wqkv, qkvbias,
                                            (void*)qkvo, 100352, 1536, 6);
  attn_mfma<<<8192, 256, 0, stream>>>(qkvo, rpb, ls, mid);
  // proj -> bf16 (window order); writes into dead qkv space
  gemm_bt<0,0,8><<<392*2, 512, 0, stream>>>(mid, wproj, pb,
                                            (void*)y_h, 100352, 512, 2);
  if (roomy){
    // x2bf only (no f32 residual round-trip)
    ln1_kernel<1><<<100352, 256, 0, stream>>>(xbf, y_h, n1g, n1b, out, mid);
    gemm_bt<2,0,8><<<392*8, 512, 0, stream>>>(mid, wfc1, f1b,
                                              (void*)big_h, 100352, 2048, 8);
    gemm_bt<0,0,32><<<392*2, 512, 0, stream>>>(big_h, wfc2, f2b,
                                               (void*)mreg, 100352, 512, 2);
    // out = x2bf + LN(m): single write of d_out
    ln2_kernel<1><<<100352, 256, 0, stream>>>(mreg, mid, n2g, n2b, out);
  } else {
    // legacy path: f32 residual in d_out, RMW in ln2
    ln1_kernel<0><<<100352, 256, 0, stream>>>(xbf, y_h, n1g, n1b, out, mid);
    gemm_bt<2,0,8><<<392*8, 512, 0, stream>>>(mid, wfc1, f1b,
                                              (void*)big_h, 100352, 2048, 8);
    gemm_bt<0,0,32><<<392*2, 512, 0, stream>>>(big_h, wfc2, f2b,
                                               (void*)mid, 100352, 512, 2);
    ln2_kernel<0><<<100352, 256, 0, stream>>>(mid, nullptr, n2g, n2b, out);
  }
}

// Round 18
// 1408.163 us; speedup vs baseline: 12.3088x; 1.0050x over previous
//
#include <hip/hip_runtime.h>

typedef unsigned short u16;
typedef unsigned int   u32;

using f32x4  = __attribute__((ext_vector_type(4))) float;
using bf16x8 = __attribute__((ext_vector_type(8))) short;  // 8 bf16 in 4 VGPRs

__device__ __forceinline__ float bf2f(u16 u){
  union { u32 i; float f; } x; x.i = ((u32)u) << 16; return x.f;
}
__device__ __forceinline__ u16 f2bf(float f){
  union { float f; u32 i; } x; x.f = f;
  u32 r = x.i + 0x7FFFu + ((x.i >> 16) & 1u);   // RNE
  return (u16)(r >> 16);
}
// tanh-form GELU, safe at +/-inf exp: tanh(u) = 1 - 2/(e^{2u}+1)
__device__ __forceinline__ float gelu_f(float v){
  float u = 0.7978845608f * v * (1.f + 0.044715f*v*v);
  float e = __expf(2.f*u);
  return 0.5f*v*(2.f - 2.f/(e + 1.f));
}

// async global->LDS, 16B per lane. LDS dest = wave-uniform base + lane*16 (HW);
// global source address is per-lane (enables row-gather + pre-swizzled staging).
__device__ __forceinline__ void glds16(const void* g, void* l){
  __builtin_amdgcn_global_load_lds(
      (const __attribute__((address_space(1))) unsigned int*)g,
      (__attribute__((address_space(3))) unsigned int*)(unsigned int)(unsigned long long)l,
      16, 0, 0);
}

// window-order token m -> source row in x (roll by -3,-3 then 7x7 window partition)
__device__ __forceinline__ int rollmap(int m){
  int win = m / 49, n = m % 49;
  int b  = win >> 6, wi = win & 63;
  int wh = wi >> 3, ww = wi & 7;
  int r = n / 7, c = n % 7;
  int sh = wh*7 + r + 3; if (sh >= 56) sh -= 56;
  int sw = ww*7 + c + 3; if (sw >= 56) sw -= 56;
  return b*3136 + sh*56 + sw;
}

// row-swizzled 16B-chunk offset within a [256 rows][32k] 64B-row region (R9-verified)
__device__ __forceinline__ int rowswz(int r, int ck){
  return ((r>>1)<<7) + (((((r&1)<<2)|ck) ^ ((r>>1)&7))<<4);
}

// ---------------- GEMM (R9 structure): C[M,N] = A[M,K] @ W[N,K]^T + bias ----
// BM=BN=256, BK=64, 512 thr / 8 waves (2Mx4N), per-wave 128x64 output.
// LDS 2 x 64KB dbuf; 4 ks-major 16KB regions [A0|A1|B0|B1]; pre-swizzled
// staging source; 4 phases/K-tile with counted vmcnt (never 0 in steady state).
// Best-measured GEMM structure of the session (R14/R17 = 1415 us total).
template<int EPI, int AMODE, int NKT>
__global__ __launch_bounds__(512, 2) void gemm_bt(const u16* __restrict__ A,
      const u16* __restrict__ Bw, const float* __restrict__ bias,
      void* __restrict__ outp, int M, int N, int nbn)
{
  constexpr int K = NKT * 64;
  __shared__ __align__(16) char LDS[2*65536];   // 128 KB
  const int t    = threadIdx.x;
  const int lane = t & 63, wave = t >> 6;
  const int wr = wave >> 2, wn = wave & 3;
  const int lr = lane & 15, lk = lane >> 4;

  const int gl = ((blockIdx.x & 7) * ((int)gridDim.x >> 3)) + (blockIdx.x >> 3);
  const int bm = gl / nbn, bn = gl - bm*nbn;

  const int q   = (t & 7) ^ ((t >> 3) & 7);
  const int sr0 = 2*(t >> 3) + (q >> 2);
  const int sch = (q & 3) * 8;
  const u16 *pA0, *pA1;
  if constexpr (AMODE == 0){
    pA0 = A + (size_t)(bm*256 + sr0      )*K + sch;
    pA1 = A + (size_t)(bm*256 + sr0 + 128)*K + sch;
  } else {
    pA0 = A + (size_t)rollmap(bm*256 + sr0      )*K + sch;
    pA1 = A + (size_t)rollmap(bm*256 + sr0 + 128)*K + sch;
  }
  const u16* pB0 = Bw + (size_t)(bn*256 + sr0      )*K + sch;
  const u16* pB1 = Bw + (size_t)(bn*256 + sr0 + 128)*K + sch;

  int oA[8], oB[4];
#pragma unroll
  for (int i = 0; i < 8; ++i) oA[i] = rowswz(wr*128 + i*16 + lr, lk);
#pragma unroll
  for (int j = 0; j < 4; ++j) oB[j] = rowswz(wn*64 + j*16 + lr, lk);

  f32x4 acc[8][4];
#pragma unroll
  for (int i = 0; i < 8; ++i)
#pragma unroll
    for (int j = 0; j < 4; ++j) acc[i][j] = (f32x4){0.f, 0.f, 0.f, 0.f};

  auto stgA = [&](int T, int ks, int buf){
    char* d = LDS + buf*65536 + ks*16384 + wave*1024;
    const int e = T*64 + ks*32;
    glds16(pA0 + e, d);
    glds16(pA1 + e, d + 8192);
  };
  auto stgB = [&](int T, int ks, int buf){
    char* d = LDS + buf*65536 + 32768 + ks*16384 + wave*1024;
    const int e = T*64 + ks*32;
    glds16(pB0 + e, d);
    glds16(pB1 + e, d + 8192);
  };

  stgA(0,0,0); stgA(0,1,0); stgB(0,0,0); stgB(0,1,0);
  stgA(1,0,1); stgA(1,1,1); stgB(1,0,1); stgB(1,1,1);
  asm volatile("s_waitcnt vmcnt(8)" ::: "memory");
  __builtin_amdgcn_s_barrier();
  asm volatile("" ::: "memory");

  auto TILE = [&](int T, int buf){
    const char* ld = LDS + buf*65536;
    const bool stP0  = (T >= 1) && (T+1 < NKT);
    const bool st123 = (T+2 < NKT);
    bf16x8 fa[4], fb[4];

#pragma unroll
    for (int j = 0; j < 4; ++j) fb[j] = *(const bf16x8*)(ld + 32768 + oB[j]);
#pragma unroll
    for (int i = 0; i < 4; ++i) fa[i] = *(const bf16x8*)(ld + oA[i]);
    if (stP0) stgA(T+1, 1, buf^1);
    __builtin_amdgcn_s_barrier();
    asm volatile("s_waitcnt lgkmcnt(0)" ::: "memory");
    __builtin_amdgcn_sched_barrier(0);
    __builtin_amdgcn_s_setprio(1);
#pragma unroll
    for (int i = 0; i < 4; ++i)
#pragma unroll
      for (int j = 0; j < 4; ++j)
        acc[i][j] = __builtin_amdgcn_mfma_f32_16x16x32_bf16(fa[i], fb[j], acc[i][j], 0, 0, 0);
    __builtin_amdgcn_s_setprio(0);
    __builtin_amdgcn_s_barrier();
    asm volatile("" ::: "memory");

#pragma unroll
    for (int i = 0; i < 4; ++i) fa[i] = *(const bf16x8*)(ld + oA[4+i]);
    if (st123) stgB(T+2, 0, buf);
    __builtin_amdgcn_s_barrier();
    asm volatile("s_waitcnt lgkmcnt(0)" ::: "memory");
    __builtin_amdgcn_sched_barrier(0);
    __builtin_amdgcn_s_setprio(1);
#pragma unroll
    for (int i = 0; i < 4; ++i)
#pragma unroll
      for (int j = 0; j < 4; ++j)
        acc[4+i][j] = __builtin_amdgcn_mfma_f32_16x16x32_bf16(fa[i], fb[j], acc[4+i][j], 0, 0, 0);
    __builtin_amdgcn_s_setprio(0);
    __builtin_amdgcn_s_barrier();
    asm volatile("" ::: "memory");

#pragma unroll
    for (int j = 0; j < 4; ++j) fb[j] = *(const bf16x8*)(ld + 49152 + oB[j]);
#pragma unroll
    for (int i = 0; i < 4; ++i) fa[i] = *(const bf16x8*)(ld + 16384 + oA[i]);
    if (st123) stgA(T+2, 0, buf);
    __builtin_amdgcn_s_barrier();
    asm volatile("s_waitcnt lgkmcnt(0)" ::: "memory");
    __builtin_amdgcn_sched_barrier(0);
    __builtin_amdgcn_s_setprio(1);
#pragma unroll
    for (int i = 0; i < 4; ++i)
#pragma unroll
      for (int j = 0; j < 4; ++j)
        acc[i][j] = __builtin_amdgcn_mfma_f32_16x16x32_bf16(fa[i], fb[j], acc[i][j], 0, 0, 0);
    __builtin_amdgcn_s_setprio(0);
    __builtin_amdgcn_s_barrier();
    asm volatile("" ::: "memory");

#pragma unroll
    for (int i = 0; i < 4; ++i) fa[i] = *(const bf16x8*)(ld + 16384 + oA[4+i]);
    if (st123) stgB(T+2, 1, buf);
    __builtin_amdgcn_s_barrier();
    asm volatile("s_waitcnt lgkmcnt(0)" ::: "memory");
    __builtin_amdgcn_sched_barrier(0);
    __builtin_amdgcn_s_setprio(1);
#pragma unroll
    for (int i = 0; i < 4; ++i)
#pragma unroll
      for (int j = 0; j < 4; ++j)
        acc[4+i][j] = __builtin_amdgcn_mfma_f32_16x16x32_bf16(fa[i], fb[j], acc[4+i][j], 0, 0, 0);
    __builtin_amdgcn_s_setprio(0);
    if (T <= NKT-3)      asm volatile("s_waitcnt vmcnt(6)" ::: "memory");
    else if (T == NKT-2) asm volatile("s_waitcnt vmcnt(0)" ::: "memory");
    if (T < NKT-1){
      __builtin_amdgcn_s_barrier();
      asm volatile("" ::: "memory");
    }
  };

  for (int p = 0; p < NKT/2; ++p){
    TILE(2*p,     0);
    TILE(2*p + 1, 1);
  }

  const int lc = lane & 15, lg = lane >> 4;
#pragma unroll
  for (int i = 0; i < 8; ++i){
#pragma unroll
    for (int j = 0; j < 4; ++j){
      int cm = bm*256 + wr*128 + i*16 + lg*4;
      int cn = bn*256 + wn*64  + j*16 + lc;
      float bv = bias[cn];
#pragma unroll
      for (int r = 0; r < 4; ++r){
        float v = acc[i][j][r] + bv;
        if (EPI == 2) v = gelu_f(v);
        ((u16*)outp)[(size_t)(cm + r)*N + cn] = f2bf(v);
      }
    }
  }
}

// ---------------- MFMA attention: 1 wave per (window, head), 4 waves/block ----
__global__ __launch_bounds__(256, 2) void attn_mfma(const u16* __restrict__ qkv,
      const float* __restrict__ rpb, const float* __restrict__ ls,
      u16* __restrict__ outp)
{
  __shared__ __align__(16) u16 Pl[4][64*72];
  __shared__ __align__(16) u16 Vl[4][32*72];
  __shared__ unsigned char regid[64];
  const int tid  = threadIdx.x, lane = tid & 63, wave = tid >> 6;
  const int lc = lane & 15, lg = lane >> 4;
  const int pair = blockIdx.x*4 + wave;
  const int win = pair >> 4, h = pair & 15;

  const u16* qb = qkv + (size_t)win*49*1536 + h*32;
  const u16* kb = qb + 512;
  const u16* vb = qb + 1024;

  if (tid < 49){
    int wi = win & 63, wh = wi >> 3, ww = wi & 7;
    int q7 = (tid*37) >> 8, r7 = tid - q7*7;
    int gh = wh*7 + q7, gw = ww*7 + r7;
    int rh = gh < 49 ? 0 : (gh < 53 ? 1 : 2);
    int rw = gw < 49 ? 0 : (gw < 53 ? 1 : 2);
    regid[tid] = (unsigned char)(rh*3 + rw);
  }

  u16* V = &Vl[wave][0];
#pragma unroll
  for (int it = 0; it < 4; ++it){
    int ch = it*64 + lane;
    int n = ch >> 2, oct = ch & 3;
    union { int4 i4; u16 s[8]; } v8;
    if (n < 49) v8.i4 = *(const int4*)(vb + (size_t)n*1536 + oct*8);
    else        v8.i4 = make_int4(0,0,0,0);
#pragma unroll
    for (int q = 0; q < 8; ++q) V[(oct*8 + q)*72 + n] = v8.s[q];
  }

  const float scale = __expf(fminf(ls[h], 4.6051702f));
  bf16x8 qf[4], kf[4];
#pragma unroll
  for (int ti = 0; ti < 4; ++ti){
    const int n = ti*16 + lc;
    {
      union { int4 i4; u16 s[8]; } raw;
      raw.i4 = *(const int4*)(qb + (size_t)n*1536 + lg*8);
      float f[8]; float ss = 0.f;
#pragma unroll
      for (int q = 0; q < 8; ++q){ f[q] = bf2f(raw.s[q]); ss += f[q]*f[q]; }
      ss += __shfl_xor(ss, 16); ss += __shfl_xor(ss, 32);
      const float inv = scale / fmaxf(sqrtf(ss), 1e-12f);
      union { short s[8]; bf16x8 v; } o;
#pragma unroll
      for (int q = 0; q < 8; ++q) o.s[q] = (short)f2bf(f[q]*inv);
      qf[ti] = o.v;
    }
    {
      union { int4 i4; u16 s[8]; } raw;
      raw.i4 = *(const int4*)(kb + (size_t)n*1536 + lg*8);
      float f[8]; float ss = 0.f;
#pragma unroll
      for (int q = 0; q < 8; ++q){ f[q] = bf2f(raw.s[q]); ss += f[q]*f[q]; }
      ss += __shfl_xor(ss, 16); ss += __shfl_xor(ss, 32);
      const float inv = 1.f / fmaxf(sqrtf(ss), 1e-12f);
      union { short s[8]; bf16x8 v; } o;
#pragma unroll
      for (int q = 0; q < 8; ++q) o.s[q] = (short)f2bf(f[q]*inv);
      kf[ti] = o.v;
    }
  }
  __syncthreads();

  f32x4 acc[4][4];
#pragma unroll
  for (int i = 0; i < 4; ++i)
#pragma unroll
    for (int j = 0; j < 4; ++j) acc[i][j] = (f32x4){0.f,0.f,0.f,0.f};
#pragma unroll
  for (int i = 0; i < 4; ++i)
#pragma unroll
    for (int j = 0; j < 4; ++j)
      acc[i][j] = __builtin_amdgcn_mfma_f32_16x16x32_bf16(qf[i], kf[j], acc[i][j], 0, 0, 0);

  u16* P = &Pl[wave][0];
  int rj[4];
#pragma unroll
  for (int tj = 0; tj < 4; ++tj){
    int j = tj*16 + lc;
    rj[tj] = (int)regid[j < 49 ? j : 0];
  }
  const float* rpbh = rpb + h*2401;
#pragma unroll
  for (int ti = 0; ti < 4; ++ti){
#pragma unroll
    for (int r = 0; r < 4; ++r){
      const int i = ti*16 + lg*4 + r;
      const bool iv = i < 49;
      const int ic = iv ? i : 0;
      const int ri = (int)regid[ic];
      const float* rrow = rpbh + ic*49;
      float sv[4];
#pragma unroll
      for (int tj = 0; tj < 4; ++tj){
        const int j = tj*16 + lc;
        float t2 = acc[ti][tj][r] + rrow[j < 49 ? j : 0];
        if (ri != rj[tj]) t2 -= 100.f;
        sv[tj] = (iv && j < 49) ? t2 : -1e30f;
      }
      float mx = fmaxf(fmaxf(sv[0],sv[1]), fmaxf(sv[2],sv[3]));
      mx = fmaxf(mx, __shfl_xor(mx, 1));
      mx = fmaxf(mx, __shfl_xor(mx, 2));
      mx = fmaxf(mx, __shfl_xor(mx, 4));
      mx = fmaxf(mx, __shfl_xor(mx, 8));
      float p[4], sum = 0.f;
#pragma unroll
      for (int tj = 0; tj < 4; ++tj){ p[tj] = __expf(sv[tj] - mx); sum += p[tj]; }
      sum += __shfl_xor(sum, 1); sum += __shfl_xor(sum, 2);
      sum += __shfl_xor(sum, 4); sum += __shfl_xor(sum, 8);
      const float rs = __builtin_amdgcn_rcpf(sum);
#pragma unroll
      for (int tj = 0; tj < 4; ++tj) P[i*72 + tj*16 + lc] = f2bf(p[tj]*rs);
    }
  }
  __syncthreads();

  f32x4 o[4][2];
#pragma unroll
  for (int i = 0; i < 4; ++i){ o[i][0] = (f32x4){0.f,0.f,0.f,0.f}; o[i][1] = (f32x4){0.f,0.f,0.f,0.f}; }
#pragma unroll
  for (int ks = 0; ks < 2; ++ks){
    bf16x8 pa[4], vf[2];
#pragma unroll
    for (int ti = 0; ti < 4; ++ti)
      pa[ti] = *(const bf16x8*)((const char*)P + (ti*16 + lc)*144 + (ks*4 + lg)*16);
#pragma unroll
    for (int tc = 0; tc < 2; ++tc)
      vf[tc] = *(const bf16x8*)((const char*)V + (tc*16 + lc)*144 + (ks*4 + lg)*16);
#pragma unroll
    for (int ti = 0; ti < 4; ++ti)
#pragma unroll
      for (int tc = 0; tc < 2; ++tc)
        o[ti][tc] = __builtin_amdgcn_mfma_f32_16x16x32_bf16(pa[ti], vf[tc], o[ti][tc], 0, 0, 0);
  }

#pragma unroll
  for (int ti = 0; ti < 4; ++ti){
#pragma unroll
    for (int tc = 0; tc < 2; ++tc){
#pragma unroll
      for (int r = 0; r < 4; ++r){
        const int i = ti*16 + lg*4 + r;
        if (i < 49)
          outp[((size_t)win*49 + i)*512 + h*32 + tc*16 + lc] = f2bf(o[ti][tc][r]);
      }
    }
  }
}

// ---------------- LN kernels ----------------
// V=0: legacy — writes xout f32 AND x2 bf16.  V=1: writes x2 bf16 only.
template<int V>
__global__ __launch_bounds__(256) void ln1_kernel(const u16* __restrict__ xb,
      const u16* __restrict__ y, const float* __restrict__ g, const float* __restrict__ bt,
      float* __restrict__ xout, u16* __restrict__ xbf)
{
  __shared__ float red[8];
  const int t = blockIdx.x;
  const int b = t / 3136, s = t % 3136;
  const int hh = s / 56, ww2 = s % 56;
  int ph = hh + 53; if (ph >= 56) ph -= 56;
  int pw = ww2 + 53; if (pw >= 56) pw -= 56;
  const int win = b*64 + (ph/7)*8 + (pw/7);
  const int n   = (ph%7)*7 + (pw%7);
  const u16* yr = y + ((size_t)win*49 + n)*512;
  const int c = threadIdx.x * 2;
  u32 u = *(const u32*)(yr + c);
  float vx = bf2f((u16)(u & 0xffff)), vy = bf2f((u16)(u >> 16));
  float sum = vx + vy, sq = vx*vx + vy*vy;
#pragma unroll
  for (int off = 32; off; off >>= 1){ sum += __shfl_xor(sum, off); sq += __shfl_xor(sq, off); }
  if ((threadIdx.x & 63) == 0){ red[threadIdx.x >> 6] = sum; red[(threadIdx.x >> 6) + 4] = sq; }
  __syncthreads();
  sum = red[0]+red[1]+red[2]+red[3];
  sq  = red[4]+red[5]+red[6]+red[7];
  const float mu  = sum * (1.f/512.f);
  const float inv = rsqrtf(fmaxf(sq * (1.f/512.f) - mu*mu, 0.f) + 1e-5f);
  u32 ux = *(const u32*)(xb + (size_t)t*512 + c);
  float o0 = bf2f((u16)(ux & 0xffff)) + (vx - mu)*inv*g[c]   + bt[c];
  float o1 = bf2f((u16)(ux >> 16))    + (vy - mu)*inv*g[c+1] + bt[c+1];
  if (V == 0){
    float* orow = xout + (size_t)t*512;
    orow[c] = o0; orow[c+1] = o1;
  }
  *(u32*)(xbf + (size_t)t*512 + c) = (u32)f2bf(o0) | ((u32)f2bf(o1) << 16);
}

// V=0: out += LN(m) (RMW on f32 out).  V=1: out = x2bf + LN(m) (single write).
template<int V>
__global__ __launch_bounds__(256) void ln2_kernel(const u16* __restrict__ m,
      const u16* __restrict__ x2b, const float* __restrict__ g,
      const float* __restrict__ bt, float* __restrict__ out)
{
  __shared__ float red[8];
  const int t = blockIdx.x;
  const int c = threadIdx.x * 2;
  u32 u = *(const u32*)(m + (size_t)t*512 + c);
  float v0 = bf2f((u16)(u & 0xffff)), v1 = bf2f((u16)(u >> 16));
  float sum = v0 + v1, sq = v0*v0 + v1*v1;
#pragma unroll
  for (int off = 32; off; off >>= 1){ sum += __shfl_xor(sum, off); sq += __shfl_xor(sq, off); }
  if ((threadIdx.x & 63) == 0){ red[threadIdx.x >> 6] = sum; red[(threadIdx.x >> 6) + 4] = sq; }
  __syncthreads();
  sum = red[0]+red[1]+red[2]+red[3];
  sq  = red[4]+red[5]+red[6]+red[7];
  const float mu  = sum * (1.f/512.f);
  const float inv = rsqrtf(fmaxf(sq * (1.f/512.f) - mu*mu, 0.f) + 1e-5f);
  float* orow = out + (size_t)t*512;
  float a0 = (v0 - mu)*inv*g[c]   + bt[c];
  float a1 = (v1 - mu)*inv*g[c+1] + bt[c+1];
  if (V == 1){
    u32 ux = *(const u32*)(x2b + (size_t)t*512 + c);
    orow[c]   = bf2f((u16)(ux & 0xffff)) + a0;
    orow[c+1] = bf2f((u16)(ux >> 16))    + a1;
  } else {
    orow[c]   += a0;
    orow[c+1] += a1;
  }
}

// ---------------- prep kernels ----------------
// merged cast of ALL four weight matrices (contiguous bf16 dest) + qkv bias.
// segments in float4 units: qkv 196608 | proj 65536 | fc1 262144 | fc2 262144.
__global__ void wcast_kernel(const float* __restrict__ qkvw, const float* __restrict__ pw,
                             const float* __restrict__ f1w,  const float* __restrict__ f2w,
                             const float* __restrict__ qb,   const float* __restrict__ vb,
                             u16* __restrict__ wout, float* __restrict__ qkvbias)
{
  int i = blockIdx.x*256 + threadIdx.x;
  if (i < 786432){
    const float* src; int off;
    if      (i < 196608){ src = qkvw; off = i; }
    else if (i < 262144){ src = pw;   off = i - 196608; }
    else if (i < 524288){ src = f1w;  off = i - 262144; }
    else                { src = f2w;  off = i - 524288; }
    float4 v = *(const float4*)(src + (size_t)off*4);
    u32 lo = (u32)f2bf(v.x) | ((u32)f2bf(v.y) << 16);
    u32 hi = (u32)f2bf(v.z) | ((u32)f2bf(v.w) << 16);
    *(uint2*)(wout + (size_t)i*4) = make_uint2(lo, hi);
  } else if (i < 786432 + 384){
    int j = (i - 786432) * 4;
    float4 o;
    float* po = (float*)&o;
#pragma unroll
    for (int k = 0; k < 4; ++k){
      int idx = j + k;
      po[k] = idx < 512 ? qb[idx] : (idx < 1024 ? 0.f : vb[idx - 1024]);
    }
    *(float4*)(qkvbias + j) = o;
  }
}
__global__ void cast_bf16_kernel(const float* __restrict__ in, u16* __restrict__ out, int n4){
  int i = blockIdx.x*256 + threadIdx.x;
  if (i >= n4) return;
  float4 v = *(const float4*)(in + (size_t)i*4);
  u32 lo = (u32)f2bf(v.x) | ((u32)f2bf(v.y) << 16);
  u32 hi = (u32)f2bf(v.z) | ((u32)f2bf(v.w) << 16);
  *(uint2*)(out + (size_t)i*4) = make_uint2(lo, hi);
}
__device__ __forceinline__ float cpb_coord(int d){
  float v = (float)(d - 6) * (8.f/6.f);
  float m = log2f(fabsf(v) + 1.f) * (1.f/3.f);
  return v > 0.f ? m : (v < 0.f ? -m : 0.f);
}
__global__ void cpb_kernel(const float* __restrict__ w1, const float* __restrict__ b1,
                           const float* __restrict__ w2, float* __restrict__ btbl){
  int idx = blockIdx.x*256 + threadIdx.x;
  if (idx >= 169*16) return;
  int e = idx >> 4, h = idx & 15;
  float t0 = cpb_coord(e / 13), t1 = cpb_coord(e % 13);
  float acc = 0.f;
  for (int jj = 0; jj < 512; ++jj){
    float hid = fmaxf(t0*w1[jj*2] + t1*w1[jj*2+1] + b1[jj], 0.f);
    acc += hid * w2[h*512 + jj];
  }
  btbl[e*16 + h] = acc;
}
__global__ void rpb_kernel(const float* __restrict__ btbl, float* __restrict__ rpb){
  int idx = blockIdx.x*256 + threadIdx.x;
  if (idx >= 16*49*49) return;
  int hh = idx / 2401, ij = idx % 2401, i = ij / 49, j = ij % 49;
  int dr = i/7 - j/7 + 6, dc = i%7 - j%7 + 6;
  float bb = btbl[(dr*13 + dc)*16 + hh];
  rpb[idx] = 16.f / (1.f + __expf(-bb));
}

// ---------------- launch ----------------
extern "C" void kernel_launch(void* const* d_in, const int* in_sizes, int n_in,
                              void* d_out, int out_size, void* d_ws, size_t ws_size,
                              hipStream_t stream)
{
  const float* x    = (const float*)d_in[0];
  const float* qkvw = (const float*)d_in[1];
  const float* qb   = (const float*)d_in[2];
  const float* vb   = (const float*)d_in[3];
  const float* ls   = (const float*)d_in[4];
  const float* cw1  = (const float*)d_in[5];
  const float* cb1  = (const float*)d_in[6];
  const float* cw2  = (const float*)d_in[7];
  const float* pw   = (const float*)d_in[8];
  const float* pb   = (const float*)d_in[9];
  const float* n1g  = (const float*)d_in[10];
  const float* n1b  = (const float*)d_in[11];
  const float* f1w  = (const float*)d_in[12];
  const float* f1b  = (const float*)d_in[13];
  const float* f2w  = (const float*)d_in[14];
  const float* f2b  = (const float*)d_in[15];
  const float* n2g  = (const float*)d_in[16];
  const float* n2b  = (const float*)d_in[17];

  char* ws = (char*)d_ws;
  const size_t SZ_BIG = (size_t)100352 * 2048 * 2;   // 411 MB big region
  const size_t SZ_MID = (size_t)100352 * 512  * 2;   // 103 MB mid region
  size_t o = SZ_BIG + SZ_MID;
  u16* wqkv  = (u16*)(ws + o); o += (size_t)1536*512*2;   // contiguous with...
  u16* wproj = (u16*)(ws + o); o += (size_t)512*512*2;    // ...
  u16* wfc1  = (u16*)(ws + o); o += (size_t)2048*512*2;   // ...
  u16* wfc2  = (u16*)(ws + o); o += (size_t)512*2048*2;   // (single wcast dest)
  float* qkvbias = (float*)(ws + o); o += 1536*4;
  float* btbl    = (float*)(ws + o); o += 2704*4;
  float* rpb     = (float*)(ws + o); o += 38416*4;

  // optional extra region for m (fc2 out) -- enables single-write d_out path
  u16* mreg = (u16*)(ws + o);
  const bool roomy = (ws_size >= o + SZ_MID);

  u16*   xbf   = (u16*)ws;
  u16*   qkvo  = (u16*)(ws + (size_t)100352*512*2);
  u16*   y_h   = qkvo;                    // reuses dead qkvo space
  u16*   big_h = (u16*)ws;
  u16*   mid   = (u16*)(ws + SZ_BIG);
  float* out   = (float*)d_out;

  // merged prep: one kernel casts all 4 weight mats (contiguous dest) + qkv bias
  wcast_kernel<<<3073, 256, 0, stream>>>(qkvw, pw, f1w, f2w, qb, vb, wqkv, qkvbias);
  cpb_kernel<<<11, 256, 0, stream>>>(cw1, cb1, cw2, btbl);
  rpb_kernel<<<151, 256, 0, stream>>>(btbl, rpb);
  cast_bf16_kernel<<<50176, 256, 0, stream>>>(x, xbf, 100352*512/4);

  // QKV: row-gathered A (roll+window fused); 256x256 tiles, K=512 (NKT=8)
  gemm_bt<0,2,8><<<392*6, 512, 0, stream>>>(xbf, wqkv, qkvbias,
                                            (void*)qkvo, 100352, 1536, 6);
  attn_mfma<<<8192, 256, 0, stream>>>(qkvo, rpb, ls, mid);
  // proj -> bf16 (window order); writes into dead qkv space
  gemm_bt<0,0,8><<<392*2, 512, 0, stream>>>(mid, wproj, pb,
                                            (void*)y_h, 100352, 512, 2);
  if (roomy){
    // x2bf only (no f32 residual round-trip)
    ln1_kernel<1><<<100352, 256, 0, stream>>>(xbf, y_h, n1g, n1b, out, mid);
    gemm_bt<2,0,8><<<392*8, 512, 0, stream>>>(mid, wfc1, f1b,
                                              (void*)big_h, 100352, 2048, 8);
    gemm_bt<0,0,32><<<392*2, 512, 0, stream>>>(big_h, wfc2, f2b,
                                               (void*)mreg, 100352, 512, 2);
    // out = x2bf + LN(m): single write of d_out
    ln2_kernel<1><<<100352, 256, 0, stream>>>(mreg, mid, n2g, n2b, out);
  } else {
    // legacy path: f32 residual in d_out, RMW in ln2
    ln1_kernel<0><<<100352, 256, 0, stream>>>(xbf, y_h, n1g, n1b, out, mid);
    gemm_bt<2,0,8><<<392*8, 512, 0, stream>>>(mid, wfc1, f1b,
                                              (void*)big_h, 100352, 2048, 8);
    gemm_bt<0,0,32><<<392*2, 512, 0, stream>>>(big_h, wfc2, f2b,
                                               (void*)mid, 100352, 512, 2);
    ln2_kernel<0><<<100352, 256, 0, stream>>>(mid, nullptr, n2g, n2b, out);
  }
}